// Round 11
// baseline (496.932 us; speedup 1.0000x reference)
//
#include <hip/hip_runtime.h>
#include <cstdint>
#include <cstddef>

#define TPB 256

namespace {

constexpr int B_SZ = 2;
constexpr int C    = 128;
constexpr int HALF = 64;
constexpr int L    = 4096;   // 64*64
constexpr int N    = 16;
constexpr int HH   = 64;
constexpr int WW   = 64;

// fast-math (hardware v_exp_f32/v_log_f32); ~1e-7 rel err, fine at 9.7e-2 threshold
__device__ __forceinline__ float softplusf(float x) {
  return fmaxf(x, 0.f) + __logf(1.f + __expf(-fabsf(x)));
}
__device__ __forceinline__ float sigm(float x) { return 1.f / (1.f + __expf(-x)); }

__device__ __forceinline__ unsigned long long unc_key(float u, int i) {
  unsigned m = __float_as_uint(u);
  m = (m & 0x80000000u) ? ~m : (m | 0x80000000u);   // monotone ascending map
  return ((unsigned long long)(~m) << 32) | (unsigned)i;  // ascending = descending unc, stable
}

// ---------- inproj: 1x1 conv, per-pixel LN from register-cached x ----------
// 1 pixel/thread, x[128] in VGPRs; O_PB=8 -> grid (16, 32, 2) = 1024 blocks.
__global__ void k_conv_ln(const float* __restrict__ X, int bsX,
                          const float* __restrict__ lnw, const float* __restrict__ lnb,
                          const float* __restrict__ W, const float* __restrict__ bias,
                          float* __restrict__ Y, int O,
                          float* __restrict__ st1s, float* __restrict__ st1q) {
  constexpr int O_PB = 8;
  constexpr int I = 128;
  __shared__ float Wl[O_PB * 128];
  __shared__ float aw[128], ab[128];
  const int o0 = blockIdx.y * O_PB;
  const int b  = blockIdx.z;
  for (int t = threadIdx.x; t < O_PB * I; t += TPB) {
    int i = t / O_PB, k = t % O_PB;
    Wl[t] = W[(size_t)(o0 + k) * I + i];
  }
  for (int t = threadIdx.x; t < I; t += TPB) { aw[t] = lnw[t]; ab[t] = lnb[t]; }
  __syncthreads();
  const int l = blockIdx.x * TPB + threadIdx.x;
  const float* X0 = X + (size_t)b * bsX + l;
  float xv[I];
  float s = 0.f, q = 0.f;
#pragma unroll
  for (int i = 0; i < I; ++i) {
    float v = X0[(size_t)i * L];
    xv[i] = v; s += v; q += v * v;
  }
  const float m = s * (1.f / I);
  const float r = rsqrtf(q * (1.f / I) - m * m + 1e-6f);
  float acc[O_PB];
#pragma unroll
  for (int k = 0; k < O_PB; ++k) acc[k] = bias[o0 + k];
#pragma unroll
  for (int i = 0; i < I; ++i) {
    float t = (xv[i] - m) * r * aw[i] + ab[i];
#pragma unroll
    for (int k = 0; k < O_PB; ++k) acc[k] += Wl[i * O_PB + k] * t;
  }
#pragma unroll
  for (int k = 0; k < O_PB; ++k)
    Y[((size_t)b * O + o0 + k) * L + l] = acc[k];
  if (o0 < 128) {
    float ss = 0.f, qq = 0.f;
#pragma unroll
    for (int k = 0; k < O_PB; ++k) { ss += acc[k]; qq += acc[k] * acc[k]; }
    atomicAdd(&st1s[b * L + l], ss);
    atomicAdd(&st1q[b * L + l], qq);
  }
}

// ---------- depthwise 3x3 + SiLU via LDS halo tile; mode0 LN (from sum/sumsq) ----------
__global__ void k_dwconv_t(const float* __restrict__ xp,
                           const float* __restrict__ st1s, const float* __restrict__ st1q,
                           const float* __restrict__ lnw, const float* __restrict__ lnb,
                           const float* __restrict__ Wm, const float* __restrict__ bm,
                           const float* __restrict__ Wr, const float* __restrict__ br,
                           float* __restrict__ xm, float* __restrict__ xr) {
  const int c = blockIdx.y;
  const int z = blockIdx.z;
  const int b = z & 1, mode = z >> 1;     // 0: mamba (LN), 1: res
  const int h0 = blockIdx.x * 4;
  __shared__ float T[6][66];
  const float* Xc = xp + ((size_t)b * 2 * C + (mode ? C + c : c)) * L;
  const float lw = mode ? 0.f : lnw[c];
  const float lb2 = mode ? 0.f : lnb[c];
  for (int t = threadIdx.x; t < 6 * 66; t += TPB) {
    int r = t / 66, cc = t % 66 - 1;
    int hh = h0 - 1 + r;
    float v = 0.f;
    if (hh >= 0 && hh < HH && cc >= 0 && cc < WW) {
      int li = hh * WW + cc;
      v = Xc[li];
      if (mode == 0) {
        float sv = st1s[b * L + li], qv = st1q[b * L + li];
        float m = sv * (1.f / 128.f);
        float rr = rsqrtf(qv * (1.f / 128.f) - m * m + 1e-6f);
        v = (v - m) * rr * lw + lb2;
      }
    }
    T[r][t % 66] = v;
  }
  __syncthreads();
  const int hl = threadIdx.x >> 6, w = threadIdx.x & 63;
  const float* W9 = (mode ? Wr : Wm) + c * 9;
  float acc = mode ? br[c] : bm[c];
#pragma unroll
  for (int kh = 0; kh < 3; ++kh)
#pragma unroll
    for (int kw = 0; kw < 3; ++kw)
      acc += T[hl + kh][w + kw] * W9[kh * 3 + kw];
  const int l = (h0 + hl) * WW + w;
  float* Yp = mode ? xr : xm;
  Yp[((size_t)b * C + c) * L + l] = acc * sigm(acc);
}

// ---------- uncertainty per pixel (deterministic fixed-order sum) ----------
__global__ void k_unc(const float* __restrict__ xm, float* __restrict__ unc) {
  const int lp = threadIdx.x & 63;
  const int wv = threadIdx.x >> 6;
  const int p  = blockIdx.x * 64 + lp;
  const int b = p / L, l = p % L;
  const float* Xp = xm + (size_t)b * C * L + l;
  float s = 0.f;
#pragma unroll 8
  for (int i = 0; i < 32; ++i) s += Xp[(size_t)(wv * 32 + i) * L];
  __shared__ float r1[4][64];
  r1[wv][lp] = s;
  __syncthreads();
  if (wv == 0) {
    float st = r1[0][lp] + r1[1][lp] + r1[2][lp] + r1[3][lp];
    float sg = sigm(st / C);
    unc[p] = -(sg * __logf(sg + 1e-6f));
  }
}

// ---------- stable rank of descending unc ----------
__global__ void k_rank(const float* __restrict__ unc, int* __restrict__ rankbuf) {
  constexpr int JC = 512;
  __shared__ unsigned long long K[JC];
  const int b  = blockIdx.z;
  const int j0 = blockIdx.y * JC;
  const int i  = blockIdx.x * TPB + threadIdx.x;
  for (int t = threadIdx.x; t < JC; t += TPB)
    K[t] = unc_key(unc[b * L + j0 + t], j0 + t);
  __syncthreads();
  const unsigned long long my = unc_key(unc[b * L + i], i);
  int cnt = 0;
#pragma unroll 8
  for (int j = 0; j < JC; ++j) cnt += (K[j] < my) ? 1 : 0;
  atomicAdd(&rankbuf[b * L + i], cnt);
}

// ---------- scatter-gather: xs[b,c,rank_l] = xm[b,c,l]; inv[l]=r; idx[r]=l ----------
__global__ void k_scatgath(const float* __restrict__ xm, const int* __restrict__ rankbuf,
                           float* __restrict__ xs, int* __restrict__ inv,
                           int* __restrict__ idx) {
  int t = blockIdx.x * TPB + threadIdx.x;
  int l = t % L, c = (t / L) % C, b = t / (C * L);
  int r = rankbuf[b * L + l];
  xs[((size_t)b * C + c) * L + r] = xm[t];
  if (c == 0) { inv[b * L + l] = r; idx[b * L + r] = l; }
}

// ---------- merged x-projection conv: z 0..3 = f/b dirs, z 4..5 = u (reads xs) ----------
__global__ void k_convx_all(const float* __restrict__ xm, const float* __restrict__ xs,
                            const float* __restrict__ Wf, const float* __restrict__ bf,
                            const float* __restrict__ Wb, const float* __restrict__ bb,
                            const float* __restrict__ Wu, const float* __restrict__ bu,
                            float* __restrict__ XDF, float* __restrict__ XDU) {
  const int z = blockIdx.z;
  const bool isU = z >= 4;
  const int I = isU ? 128 : 64;
  const int O = isU ? 40 : 36;
  const int o0 = blockIdx.y * 4;
  if (o0 >= O) return;                 // block-uniform
  int b, dir;
  const float *W, *bi;
  if (!isU) { dir = z >> 1; b = z & 1; W = dir ? Wb : Wf; bi = dir ? bb : bf; }
  else      { dir = 0; b = z - 4; W = Wu; bi = bu; }
  __shared__ float Wl[4 * 128];
  for (int t = threadIdx.x; t < 4 * I; t += TPB) {
    int i = t / 4, k = t % 4;
    Wl[t] = W[(size_t)(o0 + k) * I + i];
  }
  __syncthreads();
  const int l = blockIdx.x * TPB + threadIdx.x;
  const int ls = isU ? l : (dir ? (L - 1 - l) : l);
  const float* Xb = isU ? (xs + (size_t)b * C * L)
                        : (xm + ((size_t)b * C + dir * HALF) * L);
  float acc[4];
#pragma unroll
  for (int k = 0; k < 4; ++k) acc[k] = bi[o0 + k];
#pragma unroll 4
  for (int i = 0; i < I; ++i) {
    float xv = Xb[(size_t)i * L + ls];
#pragma unroll
    for (int k = 0; k < 4; ++k) acc[k] += Wl[i * 4 + k] * xv;
  }
  float* yp = isU ? (XDU + ((size_t)b * L + l) * 40 + o0)
                  : (XDF + ((size_t)z * L + l) * 36 + o0);
#pragma unroll
  for (int k = 0; k < 4; ++k) yp[k] = acc[k];
}

// ---------- merged fused selective scan; B/C read DIRECTLY from xdbl ----------
// bn(l,n) = xdbl[n*256 + (l>>4)][RT + (l&15)]  (16B-aligned float4 per 4 steps)
__global__ __launch_bounds__(1024) void
k_scan_all(const float* __restrict__ xdblF, const float* __restrict__ xdblU,
           const float* __restrict__ dtf_w, const float* __restrict__ dtf_b,
           const float* __restrict__ dtb_w, const float* __restrict__ dtb_b,
           const float* __restrict__ dtu_w, const float* __restrict__ dtu_b,
           const float* __restrict__ xm, const float* __restrict__ xs,
           const int* __restrict__ idx,
           const float* __restrict__ Alog_f, const float* __restrict__ Alog_b,
           const float* __restrict__ Alog_u,
           const float* __restrict__ D_f, const float* __restrict__ D_b,
           const float* __restrict__ D_u,
           float* __restrict__ yf, float* __restrict__ yb, float* __restrict__ yu) {
  const int blk = blockIdx.x;
  const int tid = threadIdx.x;
  const bool isU = blk >= 256;
  int CsT, RT, c, b, dir;
  const float *Wdt, *bdt, *Alog, *Dv, *xdbl, *Ub;
  const int* idxb = nullptr;
  float* Y;
  int OT;
  if (!isU) {
    CsT = 64; RT = 4; OT = 36;
    int zb = blk >> 6; c = blk & 63; dir = zb >> 1; b = zb & 1;
    Wdt = dir ? dtb_w : dtf_w; bdt = dir ? dtb_b : dtf_b;
    Alog = dir ? Alog_b : Alog_f; Dv = dir ? D_b : D_f;
    xdbl = xdblF + (size_t)zb * L * 36;
    Ub = xm + ((size_t)b * C + dir * HALF + c) * L;
    Y = (dir ? yb : yf) + ((size_t)b * HALF + c) * L;
  } else {
    CsT = 128; RT = 8; OT = 40;
    int blk2 = blk - 256; b = blk2 >> 7; c = blk2 & 127; dir = 0;
    Wdt = dtu_w; bdt = dtu_b; Alog = Alog_u; Dv = D_u;
    xdbl = xdblU + (size_t)b * L * 40;
    Ub = xs + ((size_t)b * C + c) * L;
    idxb = idx + b * L;
    Y = yu + ((size_t)b * C + c) * L;
  }
  __shared__ float sW[1024];          // transposed: sW[r*CsT + csrc]
  __shared__ float sb2[128];
  __shared__ float dtL[64][65];       // d
  __shared__ float uL[64][65];        // u
  __shared__ float sA[N][65], sH[N][65];
  for (int t = tid; t < CsT * RT; t += 1024) {
    int csrc = t / RT, r = t % RT;
    sW[r * CsT + csrc] = Wdt[t];
  }
  for (int t = tid; t < CsT; t += 1024) sb2[t] = bdt[t];
  __syncthreads();
  // ---- stage 1: dt + u into LDS ----
  {
    const int chunk_d = tid >> 4;
    const int sq = (tid & 15) * 4;
    const int lsrc = isU ? (c * 32 + (chunk_d >> 1)) : (c * 64 + chunk_d);
    const float* xrp = xdbl + (size_t)lsrc * OT;
    float xr[8];
    for (int r = 0; r < RT; ++r) xr[r] = xrp[r];
    const float bcc = sb2[c];
#pragma unroll
    for (int j = 0; j < 4; ++j) {
      int s = sq + j;
      int csrc = isU ? (((chunk_d & 1) << 6) + s) : s;
      float acc = sb2[csrc] + bcc;
      for (int r = 0; r < RT; ++r) acc += sW[r * CsT + csrc] * xr[r];
      int l = (chunk_d << 6) + s;
      dtL[chunk_d][s] = softplusf(acc);
      uL[chunk_d][s] = Ub[isU ? l : (dir ? (L - 1 - l) : l)];
    }
  }
  __syncthreads();
  const int n = tid & 15;
  const int chunk = tid >> 4;
  const float a = -__expf(Alog[c * N + n]);
  // phase A (B from xdbl, float4 per 4 steps)
  float ap = 1.f, h = 0.f;
#pragma unroll
  for (int sb = 0; sb < 4; ++sb) {
    const float* rp = xdbl + (size_t)((n << 8) + (chunk << 2) + sb) * OT + RT;
    float4 q0 = *(const float4*)rp;
    float4 q1 = *(const float4*)(rp + 4);
    float4 q2 = *(const float4*)(rp + 8);
    float4 q3 = *(const float4*)(rp + 12);
    float bv[16] = {q0.x, q0.y, q0.z, q0.w, q1.x, q1.y, q1.z, q1.w,
                    q2.x, q2.y, q2.z, q2.w, q3.x, q3.y, q3.z, q3.w};
#pragma unroll
    for (int j = 0; j < 16; ++j) {
      int s = (sb << 4) + j;
      float d = dtL[chunk][s];
      float uv = uL[chunk][s];
      float dA = __expf(d * a);
      ap *= dA;
      h = h * dA + d * uv * bv[j];
    }
  }
  sA[n][chunk] = ap; sH[n][chunk] = h;
  __syncthreads();
  // phase B: wave-parallel cross-chunk exclusive scan (wave w owns n=w)
  {
    const int w = tid >> 6;
    const int k = tid & 63;
    float A = sA[w][k];
    float Bv = sH[w][k];
#pragma unroll
    for (int j = 1; j < 64; j <<= 1) {
      float pa = __shfl_up(A, j);
      float pb = __shfl_up(Bv, j);
      if (k >= j) { Bv = pb * A + Bv; A = pa * A; }
    }
    float hprev = __shfl_up(Bv, 1);
    sH[w][k] = (k == 0) ? 0.f : hprev;
  }
  __syncthreads();
  h = sH[n][chunk];
  // phase C (B and C quads from xdbl)
  const float Dc = Dv[c];
  float ybuf[4];
#pragma unroll
  for (int sb = 0; sb < 4; ++sb) {
    const float* rp = xdbl + (size_t)((n << 8) + (chunk << 2) + sb) * OT + RT;
    float4 q0 = *(const float4*)rp;
    float4 q1 = *(const float4*)(rp + 4);
    float4 q2 = *(const float4*)(rp + 8);
    float4 q3 = *(const float4*)(rp + 12);
    float4 r0 = *(const float4*)(rp + 16);
    float4 r1 = *(const float4*)(rp + 20);
    float4 r2 = *(const float4*)(rp + 24);
    float4 r3 = *(const float4*)(rp + 28);
    float bv[16] = {q0.x, q0.y, q0.z, q0.w, q1.x, q1.y, q1.z, q1.w,
                    q2.x, q2.y, q2.z, q2.w, q3.x, q3.y, q3.z, q3.w};
    float cv[16] = {r0.x, r0.y, r0.z, r0.w, r1.x, r1.y, r1.z, r1.w,
                    r2.x, r2.y, r2.z, r2.w, r3.x, r3.y, r3.z, r3.w};
#pragma unroll
    for (int j = 0; j < 16; ++j) {
      int s = (sb << 4) + j;
      float d = dtL[chunk][s];
      float uv = uL[chunk][s];
      float dA = __expf(d * a);
      h = h * dA + d * uv * bv[j];
      float p = h * cv[j];
      p += __shfl_xor(p, 1);
      p += __shfl_xor(p, 2);
      p += __shfl_xor(p, 4);
      p += __shfl_xor(p, 8);
      if (j == n) ybuf[sb] = p + uv * Dc;   // s&15 == j
    }
  }
  if (!isU) {
    float* Yp = Y + (chunk << 6);
#pragma unroll
    for (int q = 0; q < 4; ++q) Yp[16 * q + n] = ybuf[q];
  } else {
    const int s0 = chunk << 6;
#pragma unroll
    for (int q = 0; q < 4; ++q) Y[idxb[s0 + 16 * q + n]] = ybuf[q];
  }
}

// ---------- gate1: inline cat-LN stats + conv + BN partial sums ----------
template <int O_PB>
__global__ void k_gate1(const float* __restrict__ yf, const float* __restrict__ yb,
                        const float* __restrict__ lncw, const float* __restrict__ lncb,
                        const float* __restrict__ yu,
                        const float* __restrict__ W, const float* __restrict__ bias,
                        float* __restrict__ g1,
                        float* __restrict__ st2m, float* __restrict__ st2r,
                        float* __restrict__ bnsum) {
  __shared__ float Wl[O_PB * 256];
  __shared__ float cw[128], cb2[128];
  __shared__ float part[2][O_PB][4];
  const int o0 = blockIdx.y * O_PB;
  const int b  = blockIdx.z;
  for (int t = threadIdx.x; t < O_PB * 256; t += TPB) {
    int i = t / O_PB, k = t % O_PB;
    Wl[t] = W[(size_t)(o0 + k) * 256 + i];
  }
  for (int t = threadIdx.x; t < 128; t += TPB) { cw[t] = lncw[t]; cb2[t] = lncb[t]; }
  __syncthreads();
  const int l = blockIdx.x * TPB + threadIdx.x;
  const float* f0 = yf + (size_t)b * HALF * L + l;
  const float* b0 = yb + (size_t)b * HALF * L + (L - 1 - l);
  const float* u0 = yu + (size_t)b * C * L + l;
  float s = 0.f, s2 = 0.f;
#pragma unroll 8
  for (int i = 0; i < 64; ++i) { float v = f0[(size_t)i * L]; s += v; s2 += v * v; }
#pragma unroll 8
  for (int i = 0; i < 64; ++i) { float v = b0[(size_t)i * L]; s += v; s2 += v * v; }
  const float m = s / C;
  const float r = rsqrtf(s2 / C - m * m + 1e-6f);
  if (blockIdx.y == 0) { st2m[b * L + l] = m; st2r[b * L + l] = r; }
  float acc[O_PB];
#pragma unroll
  for (int k = 0; k < O_PB; ++k) acc[k] = bias[o0 + k];
#pragma unroll 4
  for (int i = 0; i < 64; ++i) {
    float cv = (f0[(size_t)i * L] - m) * r * cw[i] + cb2[i];
#pragma unroll
    for (int k = 0; k < O_PB; ++k) acc[k] += Wl[i * O_PB + k] * cv;
  }
#pragma unroll 4
  for (int i = 0; i < 64; ++i) {
    float cv = (b0[(size_t)i * L] - m) * r * cw[64 + i] + cb2[64 + i];
#pragma unroll
    for (int k = 0; k < O_PB; ++k) acc[k] += Wl[(64 + i) * O_PB + k] * cv;
  }
#pragma unroll 4
  for (int i = 0; i < 128; ++i) {
    float xv = u0[(size_t)i * L];
#pragma unroll
    for (int k = 0; k < O_PB; ++k) acc[k] += Wl[(128 + i) * O_PB + k] * xv;
  }
#pragma unroll
  for (int k = 0; k < O_PB; ++k)
    g1[((size_t)b * C + o0 + k) * L + l] = acc[k];
  const int wv = threadIdx.x >> 6, lnn = threadIdx.x & 63;
#pragma unroll
  for (int k = 0; k < O_PB; ++k) {
    float v = acc[k];
    v += __shfl_xor(v, 1);  v += __shfl_xor(v, 2);  v += __shfl_xor(v, 4);
    v += __shfl_xor(v, 8);  v += __shfl_xor(v, 16); v += __shfl_xor(v, 32);
    if (lnn == 0) part[0][k][wv] = v;
    float q = acc[k] * acc[k];
    q += __shfl_xor(q, 1);  q += __shfl_xor(q, 2);  q += __shfl_xor(q, 4);
    q += __shfl_xor(q, 8);  q += __shfl_xor(q, 16); q += __shfl_xor(q, 32);
    if (lnn == 0) part[1][k][wv] = q;
  }
  __syncthreads();
  if (threadIdx.x < 2 * O_PB) {
    int which = threadIdx.x >= O_PB, k = threadIdx.x % O_PB;
    float v = part[which][k][0] + part[which][k][1] + part[which][k][2] + part[which][k][3];
    atomicAdd(&bnsum[which * 128 + o0 + k], v);
  }
}

// ---------- gate2: BN(from sums)+relu on loads; epilogue sigmoid+fuse ----------
template <int O_PB>
__global__ void k_gate2_fuse(const float* __restrict__ g1,
                             const float* __restrict__ bnsum,
                             const float* __restrict__ bn_g, const float* __restrict__ bn_b,
                             const float* __restrict__ W, const float* __restrict__ bias,
                             const float* __restrict__ yu,
                             const float* __restrict__ yf, const float* __restrict__ yb,
                             const float* __restrict__ mean2, const float* __restrict__ rinv2,
                             const float* __restrict__ lncw, const float* __restrict__ lncb,
                             float* __restrict__ fused) {
  __shared__ float Wl[O_PB * 128];
  __shared__ float sc[128], sh[128];
  __shared__ float cwo[O_PB], cbo[O_PB];
  const int o0 = blockIdx.y * O_PB;
  const int b  = blockIdx.z;
  for (int t = threadIdx.x; t < O_PB * 128; t += TPB) {
    int i = t / O_PB, k = t % O_PB;
    Wl[t] = W[(size_t)(o0 + k) * 128 + i];
  }
  for (int t = threadIdx.x; t < 128; t += TPB) {
    float sv = bnsum[t], qv = bnsum[128 + t];
    float mean = sv / (B_SZ * L);
    float var  = qv / (B_SZ * L) - mean * mean;
    float scv = bn_g[t] * rsqrtf(var + 1e-5f);
    sc[t] = scv;
    sh[t] = bn_b[t] - mean * scv;
  }
  if (threadIdx.x < O_PB) {
    cwo[threadIdx.x] = lncw[o0 + threadIdx.x];
    cbo[threadIdx.x] = lncb[o0 + threadIdx.x];
  }
  __syncthreads();
  const int l = blockIdx.x * TPB + threadIdx.x;
  const float m = mean2[b * L + l], r = rinv2[b * L + l];
  const float* Xb = g1 + (size_t)b * C * L + l;
  float acc[O_PB];
#pragma unroll
  for (int k = 0; k < O_PB; ++k) acc[k] = bias[o0 + k];
#pragma unroll 4
  for (int i = 0; i < 128; ++i) {
    float v = fmaxf(Xb[(size_t)i * L] * sc[i] + sh[i], 0.f);
#pragma unroll
    for (int k = 0; k < O_PB; ++k) acc[k] += Wl[i * O_PB + k] * v;
  }
#pragma unroll
  for (int k = 0; k < O_PB; ++k) {
    int o = o0 + k;
    float g = sigm(acc[k]);
    float yuv = yu[((size_t)b * C + o) * L + l];
    float yv = (o < 64) ? yf[((size_t)b * HALF + o) * L + l]
                        : yb[((size_t)b * HALF + (o - 64)) * L + (L - 1 - l)];
    float cv = (yv - m) * r * cwo[k] + cbo[k];
    fused[((size_t)b * C + o) * L + l] = g * yuv + (1.f - g) * cv;
  }
}

// ---------- outproj: 1x1 conv over concat([fused, xr]) ----------
template <int O_PB>
__global__ void k_conv1x1_cat2(const float* __restrict__ X1, const float* __restrict__ X2,
                               const float* __restrict__ W, const float* __restrict__ bias,
                               float* __restrict__ Y, int O) {
  __shared__ float Wl[O_PB * 256];
  const int o0 = blockIdx.y * O_PB;
  const int b  = blockIdx.z;
  for (int t = threadIdx.x; t < O_PB * 256; t += TPB) {
    int i = t / O_PB, k = t % O_PB;
    Wl[t] = W[(size_t)(o0 + k) * 256 + i];
  }
  __syncthreads();
  const int l = blockIdx.x * TPB + threadIdx.x;
  const float* Xb1 = X1 + (size_t)b * C * L + l;
  const float* Xb2 = X2 + (size_t)b * C * L + l;
  float acc[O_PB];
#pragma unroll
  for (int k = 0; k < O_PB; ++k) acc[k] = bias[o0 + k];
#pragma unroll 4
  for (int i = 0; i < 128; ++i) {
    float xv = Xb1[(size_t)i * L];
#pragma unroll
    for (int k = 0; k < O_PB; ++k) acc[k] += Wl[i * O_PB + k] * xv;
  }
#pragma unroll 4
  for (int i = 0; i < 128; ++i) {
    float xv = Xb2[(size_t)i * L];
#pragma unroll
    for (int k = 0; k < O_PB; ++k) acc[k] += Wl[(128 + i) * O_PB + k] * xv;
  }
#pragma unroll
  for (int k = 0; k < O_PB; ++k)
    Y[((size_t)b * O + o0 + k) * L + l] = acc[k];
}

// ---------- final channel LN ----------
__global__ void k_ln_cf(const float* __restrict__ X,
                        const float* __restrict__ w, const float* __restrict__ bchan,
                        float* __restrict__ Y) {
  const int lp = threadIdx.x & 63;
  const int wv = threadIdx.x >> 6;
  const int p  = blockIdx.x * 64 + lp;
  const int b = p / L, l = p % L;
  const float* Xp = X + (size_t)b * C * L + l;
  float s = 0.f, s2 = 0.f;
#pragma unroll 8
  for (int i = 0; i < 32; ++i) {
    float v = Xp[(size_t)(wv * 32 + i) * L];
    s += v; s2 += v * v;
  }
  __shared__ float r1[4][64], r2[4][64];
  r1[wv][lp] = s; r2[wv][lp] = s2;
  __syncthreads();
  float st  = r1[0][lp] + r1[1][lp] + r1[2][lp] + r1[3][lp];
  float s2t = r2[0][lp] + r2[1][lp] + r2[2][lp] + r2[3][lp];
  float mean = st / C;
  float rinv = rsqrtf(s2t / C - mean * mean + 1e-6f);
  float* Yp = Y + (size_t)b * C * L + l;
#pragma unroll 8
  for (int i = 0; i < 32; ++i) {
    int c = wv * 32 + i;
    float v = Xp[(size_t)c * L];
    Yp[(size_t)c * L] = w[c] * (v - mean) * rinv + bchan[c];
  }
}

} // namespace

extern "C" void kernel_launch(void* const* d_in, const int* in_sizes, int n_in,
                              void* d_out, int out_size, void* d_ws, size_t ws_size,
                              hipStream_t stream) {
  const float* x         = (const float*)d_in[0];
  const float* ln_in_w   = (const float*)d_in[1];
  const float* ln_in_b   = (const float*)d_in[2];
  const float* inproj_w  = (const float*)d_in[3];
  const float* inproj_b  = (const float*)d_in[4];
  const float* ln_m_w    = (const float*)d_in[5];
  const float* ln_m_b    = (const float*)d_in[6];
  const float* convm_w   = (const float*)d_in[7];
  const float* convm_b   = (const float*)d_in[8];
  const float* convr_w   = (const float*)d_in[9];
  const float* convr_b   = (const float*)d_in[10];
  const float* ln_cat_w  = (const float*)d_in[11];
  const float* ln_cat_b  = (const float*)d_in[12];
  const float* xpf_w     = (const float*)d_in[13];
  const float* xpf_b     = (const float*)d_in[14];
  const float* dtf_w     = (const float*)d_in[15];
  const float* dtf_b     = (const float*)d_in[16];
  const float* Alog_f    = (const float*)d_in[17];
  const float* D_f       = (const float*)d_in[18];
  const float* xpb_w     = (const float*)d_in[19];
  const float* xpb_b     = (const float*)d_in[20];
  const float* dtb_w     = (const float*)d_in[21];
  const float* dtb_b     = (const float*)d_in[22];
  const float* Alog_b    = (const float*)d_in[23];
  const float* D_b       = (const float*)d_in[24];
  const float* xpu_w     = (const float*)d_in[25];
  const float* xpu_b     = (const float*)d_in[26];
  const float* dtu_w     = (const float*)d_in[27];
  const float* dtu_b     = (const float*)d_in[28];
  const float* Alog_u    = (const float*)d_in[29];
  const float* D_u       = (const float*)d_in[30];
  const float* gate1_w   = (const float*)d_in[31];
  const float* gate1_b   = (const float*)d_in[32];
  const float* bn_g      = (const float*)d_in[33];
  const float* bn_b      = (const float*)d_in[34];
  const float* gate2_w   = (const float*)d_in[35];
  const float* gate2_b   = (const float*)d_in[36];
  const float* outproj_w = (const float*)d_in[37];
  const float* outproj_b = (const float*)d_in[38];
  const float* outln_w   = (const float*)d_in[39];
  const float* outln_b   = (const float*)d_in[40];

  float* ws = (float*)d_ws;
  size_t off = 0;
  auto alloc = [&](size_t n) { float* p = ws + off; off += n; return p; };

  const size_t BL = (size_t)B_SZ * L;
  // zero-initialized region (one memset): st1s, st1q, rank, bnsum — contiguous
  float* st1s  = alloc(BL);
  float* st1q  = alloc(BL);
  int*   rank  = (int*)alloc(BL);
  float* bnsum = alloc(256);
  const size_t zeroBytes = (3 * BL + 256) * sizeof(float);

  float* xp    = alloc((size_t)B_SZ * 2 * C * L);
  float* xm    = alloc((size_t)B_SZ * C * L);
  float* xr    = alloc((size_t)B_SZ * C * L);
  float* unc   = alloc(BL);
  int*   inv   = (int*)alloc(BL);
  int*   idx   = (int*)alloc(BL);
  float* xs    = alloc((size_t)B_SZ * C * L);
  float* xdblF = alloc((size_t)4 * L * 36);
  float* xdblU = alloc((size_t)2 * L * 40);
  float* yf    = alloc((size_t)B_SZ * HALF * L);
  float* yb    = alloc((size_t)B_SZ * HALF * L);
  float* yu    = alloc((size_t)B_SZ * C * L);
  float* st2m  = alloc(BL);
  float* st2r  = alloc(BL);
  float* g1    = alloc((size_t)B_SZ * C * L);
  float* fused = alloc((size_t)B_SZ * C * L);
  float* outp  = alloc((size_t)B_SZ * C * L);
  (void)ws_size; (void)in_sizes; (void)n_in; (void)out_size;

  const int pixB = B_SZ * L / 64;          // 128 blocks (256 thr)
  const int elemB = B_SZ * C * L / TPB;    // 4096

  // 0) zero the accumulators — one small async fill
  hipMemsetAsync(st1s, 0, zeroBytes, stream);
  // 1) inproj with inline LN (register-cached x) + atomic stats of xp[:,:128]
  k_conv_ln<<<dim3(L / TPB, 32, B_SZ), TPB, 0, stream>>>(
      x, C * L, ln_in_w, ln_in_b, inproj_w, inproj_b, xp, 256, st1s, st1q);
  // 2) tiled dwconv (mamba LN from sums, res plain)
  k_dwconv_t<<<dim3(HH / 4, C, 2 * B_SZ), TPB, 0, stream>>>(
      xp, st1s, st1q, ln_m_w, ln_m_b, convm_w, convm_b, convr_w, convr_b, xm, xr);
  // 3) unc, rank-count, scatter-gather (also emits idx)
  k_unc<<<pixB, TPB, 0, stream>>>(xm, unc);
  k_rank<<<dim3(L / TPB, 8, B_SZ), TPB, 0, stream>>>(unc, rank);
  k_scatgath<<<elemB, TPB, 0, stream>>>(xm, rank, xs, inv, idx);
  // 4) scan pipelines (B/C read directly from xdbl in-scan; no bc kernel)
  k_convx_all<<<dim3(L / TPB, 10, 6), TPB, 0, stream>>>(
      xm, xs, xpf_w, xpf_b, xpb_w, xpb_b, xpu_w, xpu_b, xdblF, xdblU);
  k_scan_all<<<512, 1024, 0, stream>>>(
      xdblF, xdblU, dtf_w, dtf_b, dtb_w, dtb_b, dtu_w, dtu_b,
      xm, xs, idx, Alog_f, Alog_b, Alog_u, D_f, D_b, D_u, yf, yb, yu);
  // 5) epilogue
  k_gate1<8><<<dim3(L / TPB, 16, B_SZ), TPB, 0, stream>>>(
      yf, yb, ln_cat_w, ln_cat_b, yu, gate1_w, gate1_b, g1, st2m, st2r, bnsum);
  k_gate2_fuse<8><<<dim3(L / TPB, 16, B_SZ), TPB, 0, stream>>>(
      g1, bnsum, bn_g, bn_b, gate2_w, gate2_b, yu, yf, yb, st2m, st2r,
      ln_cat_w, ln_cat_b, fused);
  k_conv1x1_cat2<8><<<dim3(L / TPB, 16, B_SZ), TPB, 0, stream>>>(
      fused, xr, outproj_w, outproj_b, outp, 128);
  k_ln_cf<<<pixB, TPB, 0, stream>>>(outp, outln_w, outln_b, (float*)d_out);
}

// Round 12
// 340.015 us; speedup vs baseline: 1.4615x; 1.4615x over previous
//
#include <hip/hip_runtime.h>
#include <cstdint>
#include <cstddef>

#define TPB 256

namespace {

constexpr int B_SZ = 2;
constexpr int C    = 128;
constexpr int HALF = 64;
constexpr int L    = 4096;   // 64*64
constexpr int N    = 16;
constexpr int HH   = 64;
constexpr int WW   = 64;

// fast-math (hardware v_exp_f32/v_log_f32); ~1e-7 rel err, fine at 9.7e-2 threshold
__device__ __forceinline__ float softplusf(float x) {
  return fmaxf(x, 0.f) + __logf(1.f + __expf(-fabsf(x)));
}
__device__ __forceinline__ float sigm(float x) { return 1.f / (1.f + __expf(-x)); }

__device__ __forceinline__ unsigned long long unc_key(float u, int i) {
  unsigned m = __float_as_uint(u);
  m = (m & 0x80000000u) ? ~m : (m | 0x80000000u);   // monotone ascending map
  return ((unsigned long long)(~m) << 32) | (unsigned)i;  // ascending = descending unc, stable
}

// ---------- inproj: 1x1 conv with INLINE per-pixel LN + atomic stats of xp[:,:128] ----------
// O_PB=8 -> 512 blocks (2/CU). 2 pixels per thread.
__global__ void k_conv_ln(const float* __restrict__ X, int bsX,
                          const float* __restrict__ lnw, const float* __restrict__ lnb,
                          const float* __restrict__ W, const float* __restrict__ bias,
                          float* __restrict__ Y, int I, int O,
                          float* __restrict__ st1s, float* __restrict__ st1q) {
  constexpr int O_PB = 8;
  __shared__ float Wl[O_PB * 128];
  __shared__ float aw[128], ab[128];
  const int o0 = blockIdx.y * O_PB;
  const int b  = blockIdx.z;
  for (int t = threadIdx.x; t < O_PB * I; t += TPB) {
    int i = t / O_PB, k = t % O_PB;
    Wl[t] = W[(size_t)(o0 + k) * I + i];
  }
  for (int t = threadIdx.x; t < I; t += TPB) { aw[t] = lnw[t]; ab[t] = lnb[t]; }
  __syncthreads();
  const int l0 = blockIdx.x * (2 * TPB) + threadIdx.x;
  const int l1 = l0 + TPB;
  const float* X0 = X + (size_t)b * bsX + l0;
  const float* X1 = X + (size_t)b * bsX + l1;
  float s0 = 0.f, q0 = 0.f, s1 = 0.f, q1 = 0.f;
#pragma unroll 8
  for (int i = 0; i < I; ++i) {
    float v0 = X0[(size_t)i * L], v1 = X1[(size_t)i * L];
    s0 += v0; q0 += v0 * v0; s1 += v1; q1 += v1 * v1;
  }
  const float m0 = s0 / I, m1 = s1 / I;
  const float r0 = rsqrtf(q0 / I - m0 * m0 + 1e-6f);
  const float r1 = rsqrtf(q1 / I - m1 * m1 + 1e-6f);
  float acc0[O_PB], acc1[O_PB];
#pragma unroll
  for (int k = 0; k < O_PB; ++k) { acc0[k] = bias[o0 + k]; acc1[k] = acc0[k]; }
#pragma unroll 4
  for (int i = 0; i < I; ++i) {
    float xv0 = (X0[(size_t)i * L] - m0) * r0 * aw[i] + ab[i];
    float xv1 = (X1[(size_t)i * L] - m1) * r1 * aw[i] + ab[i];
#pragma unroll
    for (int k = 0; k < O_PB; ++k) {
      acc0[k] += Wl[i * O_PB + k] * xv0;
      acc1[k] += Wl[i * O_PB + k] * xv1;
    }
  }
#pragma unroll
  for (int k = 0; k < O_PB; ++k) {
    Y[((size_t)b * O + o0 + k) * L + l0] = acc0[k];
    Y[((size_t)b * O + o0 + k) * L + l1] = acc1[k];
  }
  // atomic partial stats of the first 128 output channels (feeds LN-mamba)
  if (o0 < 128) {
    float ss0 = 0.f, qq0 = 0.f, ss1 = 0.f, qq1 = 0.f;
#pragma unroll
    for (int k = 0; k < O_PB; ++k) {
      ss0 += acc0[k]; qq0 += acc0[k] * acc0[k];
      ss1 += acc1[k]; qq1 += acc1[k] * acc1[k];
    }
    atomicAdd(&st1s[b * L + l0], ss0);
    atomicAdd(&st1q[b * L + l0], qq0);
    atomicAdd(&st1s[b * L + l1], ss1);
    atomicAdd(&st1q[b * L + l1], qq1);
  }
}

// ---------- depthwise 3x3 + SiLU via LDS halo tile; mode0 LN (from sum/sumsq) ----------
__global__ void k_dwconv_t(const float* __restrict__ xp,
                           const float* __restrict__ st1s, const float* __restrict__ st1q,
                           const float* __restrict__ lnw, const float* __restrict__ lnb,
                           const float* __restrict__ Wm, const float* __restrict__ bm,
                           const float* __restrict__ Wr, const float* __restrict__ br,
                           float* __restrict__ xm, float* __restrict__ xr) {
  const int c = blockIdx.y;
  const int z = blockIdx.z;
  const int b = z & 1, mode = z >> 1;     // 0: mamba (LN), 1: res
  const int h0 = blockIdx.x * 4;
  __shared__ float T[6][66];
  const float* Xc = xp + ((size_t)b * 2 * C + (mode ? C + c : c)) * L;
  const float lw = mode ? 0.f : lnw[c];
  const float lb2 = mode ? 0.f : lnb[c];
  for (int t = threadIdx.x; t < 6 * 66; t += TPB) {
    int r = t / 66, cc = t % 66 - 1;
    int hh = h0 - 1 + r;
    float v = 0.f;
    if (hh >= 0 && hh < HH && cc >= 0 && cc < WW) {
      int li = hh * WW + cc;
      v = Xc[li];
      if (mode == 0) {
        float sv = st1s[b * L + li], qv = st1q[b * L + li];
        float m = sv * (1.f / 128.f);
        float rr = rsqrtf(qv * (1.f / 128.f) - m * m + 1e-6f);
        v = (v - m) * rr * lw + lb2;
      }
    }
    T[r][t % 66] = v;
  }
  __syncthreads();
  const int hl = threadIdx.x >> 6, w = threadIdx.x & 63;
  const float* W9 = (mode ? Wr : Wm) + c * 9;
  float acc = mode ? br[c] : bm[c];
#pragma unroll
  for (int kh = 0; kh < 3; ++kh)
#pragma unroll
    for (int kw = 0; kw < 3; ++kw)
      acc += T[hl + kh][w + kw] * W9[kh * 3 + kw];
  const int l = (h0 + hl) * WW + w;
  float* Yp = mode ? xr : xm;
  Yp[((size_t)b * C + c) * L + l] = acc * sigm(acc);
}

// ---------- uncertainty per pixel ----------
__global__ void k_unc(const float* __restrict__ xm, float* __restrict__ unc) {
  const int lp = threadIdx.x & 63;
  const int wv = threadIdx.x >> 6;
  const int p  = blockIdx.x * 64 + lp;
  const int b = p / L, l = p % L;
  const float* Xp = xm + (size_t)b * C * L + l;
  float s = 0.f;
#pragma unroll 8
  for (int i = 0; i < 32; ++i) s += Xp[(size_t)(wv * 32 + i) * L];
  __shared__ float r1[4][64];
  r1[wv][lp] = s;
  __syncthreads();
  if (wv == 0) {
    float st = r1[0][lp] + r1[1][lp] + r1[2][lp] + r1[3][lp];
    float sg = sigm(st / C);
    unc[p] = -(sg * __logf(sg + 1e-6f));
  }
}

// ---------- stable rank of descending unc: rank_i = #{j: ckey_j < ckey_i} ----------
__global__ void k_rank(const float* __restrict__ unc, int* __restrict__ rankbuf) {
  constexpr int JC = 512;
  __shared__ unsigned long long K[JC];
  const int b  = blockIdx.z;
  const int j0 = blockIdx.y * JC;
  const int i  = blockIdx.x * TPB + threadIdx.x;
  for (int t = threadIdx.x; t < JC; t += TPB)
    K[t] = unc_key(unc[b * L + j0 + t], j0 + t);
  __syncthreads();
  const unsigned long long my = unc_key(unc[b * L + i], i);
  int cnt = 0;
#pragma unroll 8
  for (int j = 0; j < JC; ++j) cnt += (K[j] < my) ? 1 : 0;
  atomicAdd(&rankbuf[b * L + i], cnt);
}

// ---------- scatter-gather: xs[b,c,rank_l] = xm[b,c,l]; inv[l]=r; idx[r]=l ----------
__global__ void k_scatgath(const float* __restrict__ xm, const int* __restrict__ rankbuf,
                           float* __restrict__ xs, int* __restrict__ inv,
                           int* __restrict__ idx) {
  int t = blockIdx.x * TPB + threadIdx.x;
  int l = t % L, c = (t / L) % C, b = t / (C * L);
  int r = rankbuf[b * L + l];
  xs[((size_t)b * C + c) * L + r] = xm[t];
  if (c == 0) { inv[b * L + l] = r; idx[b * L + r] = l; }
}

// ---------- merged x-projection conv: z 0..3 = f/b dirs, z 4..5 = u (reads xs) ----------
__global__ void k_convx_all(const float* __restrict__ xm, const float* __restrict__ xs,
                            const float* __restrict__ Wf, const float* __restrict__ bf,
                            const float* __restrict__ Wb, const float* __restrict__ bb,
                            const float* __restrict__ Wu, const float* __restrict__ bu,
                            float* __restrict__ XDF, float* __restrict__ XDU) {
  const int z = blockIdx.z;
  const bool isU = z >= 4;
  const int I = isU ? 128 : 64;
  const int O = isU ? 40 : 36;
  const int o0 = blockIdx.y * 4;
  if (o0 >= O) return;                 // block-uniform
  int b, dir;
  const float *W, *bi;
  if (!isU) { dir = z >> 1; b = z & 1; W = dir ? Wb : Wf; bi = dir ? bb : bf; }
  else      { dir = 0; b = z - 4; W = Wu; bi = bu; }
  __shared__ float Wl[4 * 128];
  for (int t = threadIdx.x; t < 4 * I; t += TPB) {
    int i = t / 4, k = t % 4;
    Wl[t] = W[(size_t)(o0 + k) * I + i];
  }
  __syncthreads();
  const int l = blockIdx.x * TPB + threadIdx.x;
  const int ls = isU ? l : (dir ? (L - 1 - l) : l);
  const float* Xb = isU ? (xs + (size_t)b * C * L)
                        : (xm + ((size_t)b * C + dir * HALF) * L);
  float acc[4];
#pragma unroll
  for (int k = 0; k < 4; ++k) acc[k] = bi[o0 + k];
#pragma unroll 4
  for (int i = 0; i < I; ++i) {
    float xv = Xb[(size_t)i * L + ls];
#pragma unroll
    for (int k = 0; k < 4; ++k) acc[k] += Wl[i * 4 + k] * xv;
  }
  float* yp = isU ? (XDU + ((size_t)b * L + l) * 40 + o0)
                  : (XDF + ((size_t)z * L + l) * 36 + o0);
#pragma unroll
  for (int k = 0; k < 4; ++k) yp[k] = acc[k];
}

// ---------- merged B/C scrambled transpose ----------
__global__ void k_bc_all(const float* __restrict__ xdblF, const float* __restrict__ xdblU,
                         float* __restrict__ BmTF, float* __restrict__ CmTF,
                         float* __restrict__ BmTU, float* __restrict__ CmTU) {
  const int z = blockIdx.z;
  const bool isU = z >= 4;
  const int RT = isU ? 8 : 4, OT = isU ? 40 : 36;
  const float* src = isU ? (xdblU + (size_t)(z - 4) * L * 40)
                         : (xdblF + (size_t)z * L * 36);
  float* BT = isU ? (BmTU + (size_t)(z - 4) * L * N) : (BmTF + (size_t)z * L * N);
  float* CT = isU ? (CmTU + (size_t)(z - 4) * L * N) : (CmTF + (size_t)z * L * N);
  const int n = blockIdx.y;
  const int l2 = blockIdx.x * TPB + threadIdx.x;
  int f2 = n * L + l2;
  int lb = f2 >> 4, cb = f2 & 15;
  const float* xr2 = src + (size_t)lb * OT + RT + cb;
  size_t ob = (size_t)l2 * N + n;
  BT[ob] = xr2[0];
  CT[ob] = xr2[N];
}

// ---------- merged fused selective scan (512 blocks); U writes UNSORTED via idx ----------
__global__ __launch_bounds__(1024) void
k_scan_all(const float* __restrict__ xdblF, const float* __restrict__ xdblU,
           const float* __restrict__ dtf_w, const float* __restrict__ dtf_b,
           const float* __restrict__ dtb_w, const float* __restrict__ dtb_b,
           const float* __restrict__ dtu_w, const float* __restrict__ dtu_b,
           const float* __restrict__ xm, const float* __restrict__ xs,
           const int* __restrict__ idx,
           const float* __restrict__ BmTF, const float* __restrict__ CmTF,
           const float* __restrict__ BmTU, const float* __restrict__ CmTU,
           const float* __restrict__ Alog_f, const float* __restrict__ Alog_b,
           const float* __restrict__ Alog_u,
           const float* __restrict__ D_f, const float* __restrict__ D_b,
           const float* __restrict__ D_u,
           float* __restrict__ yf, float* __restrict__ yb, float* __restrict__ yu) {
  const int blk = blockIdx.x;
  const int tid = threadIdx.x;
  const bool isU = blk >= 256;
  int CsT, RT, c, b, dir;
  const float *Wdt, *bdt, *Alog, *Dv, *xdbl, *BT, *CT, *Ub;
  const int* idxb = nullptr;
  float* Y;
  int OT;
  if (!isU) {
    CsT = 64; RT = 4; OT = 36;
    int zb = blk >> 6; c = blk & 63; dir = zb >> 1; b = zb & 1;
    Wdt = dir ? dtb_w : dtf_w; bdt = dir ? dtb_b : dtf_b;
    Alog = dir ? Alog_b : Alog_f; Dv = dir ? D_b : D_f;
    xdbl = xdblF + (size_t)zb * L * 36;
    BT = BmTF + (size_t)zb * L * N; CT = CmTF + (size_t)zb * L * N;
    Ub = xm + ((size_t)b * C + dir * HALF + c) * L;
    Y = (dir ? yb : yf) + ((size_t)b * HALF + c) * L;
  } else {
    CsT = 128; RT = 8; OT = 40;
    int blk2 = blk - 256; b = blk2 >> 7; c = blk2 & 127; dir = 0;
    Wdt = dtu_w; bdt = dtu_b; Alog = Alog_u; Dv = D_u;
    xdbl = xdblU + (size_t)b * L * 40;
    BT = BmTU + (size_t)b * L * N; CT = CmTU + (size_t)b * L * N;
    Ub = xs + ((size_t)b * C + c) * L;
    idxb = idx + b * L;
    Y = yu + ((size_t)b * C + c) * L;
  }
  __shared__ float sW[1024];          // transposed: sW[r*CsT + csrc]
  __shared__ float sb2[128];
  __shared__ float dtL[64][65];       // d
  __shared__ float uL[64][65];        // u
  __shared__ float sA[N][65], sH[N][65];
  for (int t = tid; t < CsT * RT; t += 1024) {
    int csrc = t / RT, r = t % RT;
    sW[r * CsT + csrc] = Wdt[t];
  }
  for (int t = tid; t < CsT; t += 1024) sb2[t] = bdt[t];
  __syncthreads();
  // ---- stage 1: dt + u into LDS ----
  {
    const int chunk_d = tid >> 4;
    const int sq = (tid & 15) * 4;
    const int lsrc = isU ? (c * 32 + (chunk_d >> 1)) : (c * 64 + chunk_d);
    const float* xrp = xdbl + (size_t)lsrc * OT;
    float xr[8];
    for (int r = 0; r < RT; ++r) xr[r] = xrp[r];
    const float bcc = sb2[c];
#pragma unroll
    for (int j = 0; j < 4; ++j) {
      int s = sq + j;
      int csrc = isU ? (((chunk_d & 1) << 6) + s) : s;
      float acc = sb2[csrc] + bcc;
      for (int r = 0; r < RT; ++r) acc += sW[r * CsT + csrc] * xr[r];
      int l = (chunk_d << 6) + s;
      dtL[chunk_d][s] = softplusf(acc);
      uL[chunk_d][s] = Ub[isU ? l : (dir ? (L - 1 - l) : l)];
    }
  }
  __syncthreads();
  const int n = tid & 15;
  const int chunk = tid >> 4;
  const float a = -__expf(Alog[c * N + n]);
  const float* bp = BT + ((size_t)(chunk << 6)) * N + n;
  const float* cp = CT + ((size_t)(chunk << 6)) * N + n;
  // phase A
  float ap = 1.f, h = 0.f;
#pragma unroll 4
  for (int s = 0; s < 64; ++s) {
    float d = dtL[chunk][s];
    float uv = uL[chunk][s];
    float bn = bp[(size_t)s * N];
    float dA = __expf(d * a);
    ap *= dA;
    h = h * dA + d * uv * bn;
  }
  sA[n][chunk] = ap; sH[n][chunk] = h;
  __syncthreads();
  // phase B: wave-parallel cross-chunk exclusive scan (wave w owns n=w)
  {
    const int w = tid >> 6;
    const int k = tid & 63;
    float A = sA[w][k];
    float Bv = sH[w][k];
#pragma unroll
    for (int j = 1; j < 64; j <<= 1) {
      float pa = __shfl_up(A, j);
      float pb = __shfl_up(Bv, j);
      if (k >= j) { Bv = pb * A + Bv; A = pa * A; }
    }
    float hprev = __shfl_up(Bv, 1);
    sH[w][k] = (k == 0) ? 0.f : hprev;
  }
  __syncthreads();
  h = sH[n][chunk];
  // phase C
  const float Dc = Dv[c];
  float ybuf[4];
#pragma unroll 4
  for (int s = 0; s < 64; ++s) {
    float d = dtL[chunk][s];
    float uv = uL[chunk][s];
    float bn = bp[(size_t)s * N];
    float cn = cp[(size_t)s * N];
    float dA = __expf(d * a);
    h = h * dA + d * uv * bn;
    float p = h * cn;
    p += __shfl_xor(p, 1);
    p += __shfl_xor(p, 2);
    p += __shfl_xor(p, 4);
    p += __shfl_xor(p, 8);
    if ((s & 15) == n) ybuf[s >> 4] = p + uv * Dc;
  }
  if (!isU) {
    float* Yp = Y + (chunk << 6);
#pragma unroll
    for (int q = 0; q < 4; ++q) Yp[16 * q + n] = ybuf[q];
  } else {
    const int s0 = chunk << 6;
#pragma unroll
    for (int q = 0; q < 4; ++q) Y[idxb[s0 + 16 * q + n]] = ybuf[q];
  }
}

// ---------- gate1: inline cat-LN stats + conv + BN partial sums ----------
template <int O_PB>
__global__ void k_gate1(const float* __restrict__ yf, const float* __restrict__ yb,
                        const float* __restrict__ lncw, const float* __restrict__ lncb,
                        const float* __restrict__ yu,
                        const float* __restrict__ W, const float* __restrict__ bias,
                        float* __restrict__ g1,
                        float* __restrict__ st2m, float* __restrict__ st2r,
                        float* __restrict__ bnsum) {
  __shared__ float Wl[O_PB * 256];
  __shared__ float cw[128], cb2[128];
  __shared__ float part[2][O_PB][4];
  const int o0 = blockIdx.y * O_PB;
  const int b  = blockIdx.z;
  for (int t = threadIdx.x; t < O_PB * 256; t += TPB) {
    int i = t / O_PB, k = t % O_PB;
    Wl[t] = W[(size_t)(o0 + k) * 256 + i];
  }
  for (int t = threadIdx.x; t < 128; t += TPB) { cw[t] = lncw[t]; cb2[t] = lncb[t]; }
  __syncthreads();
  const int l = blockIdx.x * TPB + threadIdx.x;
  const float* f0 = yf + (size_t)b * HALF * L + l;
  const float* b0 = yb + (size_t)b * HALF * L + (L - 1 - l);
  const float* u0 = yu + (size_t)b * C * L + l;
  float s = 0.f, s2 = 0.f;
#pragma unroll 8
  for (int i = 0; i < 64; ++i) { float v = f0[(size_t)i * L]; s += v; s2 += v * v; }
#pragma unroll 8
  for (int i = 0; i < 64; ++i) { float v = b0[(size_t)i * L]; s += v; s2 += v * v; }
  const float m = s / C;
  const float r = rsqrtf(s2 / C - m * m + 1e-6f);
  if (blockIdx.y == 0) { st2m[b * L + l] = m; st2r[b * L + l] = r; }
  float acc[O_PB];
#pragma unroll
  for (int k = 0; k < O_PB; ++k) acc[k] = bias[o0 + k];
#pragma unroll 4
  for (int i = 0; i < 64; ++i) {
    float cv = (f0[(size_t)i * L] - m) * r * cw[i] + cb2[i];
#pragma unroll
    for (int k = 0; k < O_PB; ++k) acc[k] += Wl[i * O_PB + k] * cv;
  }
#pragma unroll 4
  for (int i = 0; i < 64; ++i) {
    float cv = (b0[(size_t)i * L] - m) * r * cw[64 + i] + cb2[64 + i];
#pragma unroll
    for (int k = 0; k < O_PB; ++k) acc[k] += Wl[(64 + i) * O_PB + k] * cv;
  }
#pragma unroll 4
  for (int i = 0; i < 128; ++i) {
    float xv = u0[(size_t)i * L];
#pragma unroll
    for (int k = 0; k < O_PB; ++k) acc[k] += Wl[(128 + i) * O_PB + k] * xv;
  }
#pragma unroll
  for (int k = 0; k < O_PB; ++k)
    g1[((size_t)b * C + o0 + k) * L + l] = acc[k];
  const int wv = threadIdx.x >> 6, lnn = threadIdx.x & 63;
#pragma unroll
  for (int k = 0; k < O_PB; ++k) {
    float v = acc[k];
    v += __shfl_xor(v, 1);  v += __shfl_xor(v, 2);  v += __shfl_xor(v, 4);
    v += __shfl_xor(v, 8);  v += __shfl_xor(v, 16); v += __shfl_xor(v, 32);
    if (lnn == 0) part[0][k][wv] = v;
    float q = acc[k] * acc[k];
    q += __shfl_xor(q, 1);  q += __shfl_xor(q, 2);  q += __shfl_xor(q, 4);
    q += __shfl_xor(q, 8);  q += __shfl_xor(q, 16); q += __shfl_xor(q, 32);
    if (lnn == 0) part[1][k][wv] = q;
  }
  __syncthreads();
  if (threadIdx.x < 2 * O_PB) {
    int which = threadIdx.x >= O_PB, k = threadIdx.x % O_PB;
    float v = part[which][k][0] + part[which][k][1] + part[which][k][2] + part[which][k][3];
    atomicAdd(&bnsum[which * 128 + o0 + k], v);
  }
}

// ---------- gate2: BN(from sums)+relu on loads; epilogue sigmoid+fuse ----------
template <int O_PB>
__global__ void k_gate2_fuse(const float* __restrict__ g1,
                             const float* __restrict__ bnsum,
                             const float* __restrict__ bn_g, const float* __restrict__ bn_b,
                             const float* __restrict__ W, const float* __restrict__ bias,
                             const float* __restrict__ yu,
                             const float* __restrict__ yf, const float* __restrict__ yb,
                             const float* __restrict__ mean2, const float* __restrict__ rinv2,
                             const float* __restrict__ lncw, const float* __restrict__ lncb,
                             float* __restrict__ fused) {
  __shared__ float Wl[O_PB * 128];
  __shared__ float sc[128], sh[128];
  __shared__ float cwo[O_PB], cbo[O_PB];
  const int o0 = blockIdx.y * O_PB;
  const int b  = blockIdx.z;
  for (int t = threadIdx.x; t < O_PB * 128; t += TPB) {
    int i = t / O_PB, k = t % O_PB;
    Wl[t] = W[(size_t)(o0 + k) * 128 + i];
  }
  for (int t = threadIdx.x; t < 128; t += TPB) {
    float sv = bnsum[t], qv = bnsum[128 + t];
    float mean = sv / (B_SZ * L);
    float var  = qv / (B_SZ * L) - mean * mean;
    float scv = bn_g[t] * rsqrtf(var + 1e-5f);
    sc[t] = scv;
    sh[t] = bn_b[t] - mean * scv;
  }
  if (threadIdx.x < O_PB) {
    cwo[threadIdx.x] = lncw[o0 + threadIdx.x];
    cbo[threadIdx.x] = lncb[o0 + threadIdx.x];
  }
  __syncthreads();
  const int l = blockIdx.x * TPB + threadIdx.x;
  const float m = mean2[b * L + l], r = rinv2[b * L + l];
  const float* Xb = g1 + (size_t)b * C * L + l;
  float acc[O_PB];
#pragma unroll
  for (int k = 0; k < O_PB; ++k) acc[k] = bias[o0 + k];
#pragma unroll 4
  for (int i = 0; i < 128; ++i) {
    float v = fmaxf(Xb[(size_t)i * L] * sc[i] + sh[i], 0.f);
#pragma unroll
    for (int k = 0; k < O_PB; ++k) acc[k] += Wl[i * O_PB + k] * v;
  }
#pragma unroll
  for (int k = 0; k < O_PB; ++k) {
    int o = o0 + k;
    float g = sigm(acc[k]);
    float yuv = yu[((size_t)b * C + o) * L + l];
    float yv = (o < 64) ? yf[((size_t)b * HALF + o) * L + l]
                        : yb[((size_t)b * HALF + (o - 64)) * L + (L - 1 - l)];
    float cv = (yv - m) * r * cwo[k] + cbo[k];
    fused[((size_t)b * C + o) * L + l] = g * yuv + (1.f - g) * cv;
  }
}

// ---------- outproj: 1x1 conv over concat([fused, xr]) ----------
template <int O_PB>
__global__ void k_conv1x1_cat2(const float* __restrict__ X1, const float* __restrict__ X2,
                               const float* __restrict__ W, const float* __restrict__ bias,
                               float* __restrict__ Y, int O) {
  __shared__ float Wl[O_PB * 256];
  const int o0 = blockIdx.y * O_PB;
  const int b  = blockIdx.z;
  for (int t = threadIdx.x; t < O_PB * 256; t += TPB) {
    int i = t / O_PB, k = t % O_PB;
    Wl[t] = W[(size_t)(o0 + k) * 256 + i];
  }
  __syncthreads();
  const int l = blockIdx.x * TPB + threadIdx.x;
  const float* Xb1 = X1 + (size_t)b * C * L + l;
  const float* Xb2 = X2 + (size_t)b * C * L + l;
  float acc[O_PB];
#pragma unroll
  for (int k = 0; k < O_PB; ++k) acc[k] = bias[o0 + k];
#pragma unroll 4
  for (int i = 0; i < 128; ++i) {
    float xv = Xb1[(size_t)i * L];
#pragma unroll
    for (int k = 0; k < O_PB; ++k) acc[k] += Wl[i * O_PB + k] * xv;
  }
#pragma unroll 4
  for (int i = 0; i < 128; ++i) {
    float xv = Xb2[(size_t)i * L];
#pragma unroll
    for (int k = 0; k < O_PB; ++k) acc[k] += Wl[(128 + i) * O_PB + k] * xv;
  }
#pragma unroll
  for (int k = 0; k < O_PB; ++k)
    Y[((size_t)b * O + o0 + k) * L + l] = acc[k];
}

// ---------- final channel LN ----------
__global__ void k_ln_cf(const float* __restrict__ X,
                        const float* __restrict__ w, const float* __restrict__ bchan,
                        float* __restrict__ Y) {
  const int lp = threadIdx.x & 63;
  const int wv = threadIdx.x >> 6;
  const int p  = blockIdx.x * 64 + lp;
  const int b = p / L, l = p % L;
  const float* Xp = X + (size_t)b * C * L + l;
  float s = 0.f, s2 = 0.f;
#pragma unroll 8
  for (int i = 0; i < 32; ++i) {
    float v = Xp[(size_t)(wv * 32 + i) * L];
    s += v; s2 += v * v;
  }
  __shared__ float r1[4][64], r2[4][64];
  r1[wv][lp] = s; r2[wv][lp] = s2;
  __syncthreads();
  float st  = r1[0][lp] + r1[1][lp] + r1[2][lp] + r1[3][lp];
  float s2t = r2[0][lp] + r2[1][lp] + r2[2][lp] + r2[3][lp];
  float mean = st / C;
  float rinv = rsqrtf(s2t / C - mean * mean + 1e-6f);
  float* Yp = Y + (size_t)b * C * L + l;
#pragma unroll 8
  for (int i = 0; i < 32; ++i) {
    int c = wv * 32 + i;
    float v = Xp[(size_t)c * L];
    Yp[(size_t)c * L] = w[c] * (v - mean) * rinv + bchan[c];
  }
}

} // namespace

extern "C" void kernel_launch(void* const* d_in, const int* in_sizes, int n_in,
                              void* d_out, int out_size, void* d_ws, size_t ws_size,
                              hipStream_t stream) {
  const float* x         = (const float*)d_in[0];
  const float* ln_in_w   = (const float*)d_in[1];
  const float* ln_in_b   = (const float*)d_in[2];
  const float* inproj_w  = (const float*)d_in[3];
  const float* inproj_b  = (const float*)d_in[4];
  const float* ln_m_w    = (const float*)d_in[5];
  const float* ln_m_b    = (const float*)d_in[6];
  const float* convm_w   = (const float*)d_in[7];
  const float* convm_b   = (const float*)d_in[8];
  const float* convr_w   = (const float*)d_in[9];
  const float* convr_b   = (const float*)d_in[10];
  const float* ln_cat_w  = (const float*)d_in[11];
  const float* ln_cat_b  = (const float*)d_in[12];
  const float* xpf_w     = (const float*)d_in[13];
  const float* xpf_b     = (const float*)d_in[14];
  const float* dtf_w     = (const float*)d_in[15];
  const float* dtf_b     = (const float*)d_in[16];
  const float* Alog_f    = (const float*)d_in[17];
  const float* D_f       = (const float*)d_in[18];
  const float* xpb_w     = (const float*)d_in[19];
  const float* xpb_b     = (const float*)d_in[20];
  const float* dtb_w     = (const float*)d_in[21];
  const float* dtb_b     = (const float*)d_in[22];
  const float* Alog_b    = (const float*)d_in[23];
  const float* D_b       = (const float*)d_in[24];
  const float* xpu_w     = (const float*)d_in[25];
  const float* xpu_b     = (const float*)d_in[26];
  const float* dtu_w     = (const float*)d_in[27];
  const float* dtu_b     = (const float*)d_in[28];
  const float* Alog_u    = (const float*)d_in[29];
  const float* D_u       = (const float*)d_in[30];
  const float* gate1_w   = (const float*)d_in[31];
  const float* gate1_b   = (const float*)d_in[32];
  const float* bn_g      = (const float*)d_in[33];
  const float* bn_b      = (const float*)d_in[34];
  const float* gate2_w   = (const float*)d_in[35];
  const float* gate2_b   = (const float*)d_in[36];
  const float* outproj_w = (const float*)d_in[37];
  const float* outproj_b = (const float*)d_in[38];
  const float* outln_w   = (const float*)d_in[39];
  const float* outln_b   = (const float*)d_in[40];

  float* ws = (float*)d_ws;
  size_t off = 0;
  auto alloc = [&](size_t n) { float* p = ws + off; off += n; return p; };

  const size_t BL = (size_t)B_SZ * L;
  // zero-initialized region (one memset): st1s, st1q, rank, bnsum — contiguous
  float* st1s  = alloc(BL);
  float* st1q  = alloc(BL);
  int*   rank  = (int*)alloc(BL);
  float* bnsum = alloc(256);
  const size_t zeroBytes = (3 * BL + 256) * sizeof(float);

  float* xp    = alloc((size_t)B_SZ * 2 * C * L);
  float* xm    = alloc((size_t)B_SZ * C * L);
  float* xr    = alloc((size_t)B_SZ * C * L);
  float* unc   = alloc(BL);
  int*   inv   = (int*)alloc(BL);
  int*   idx   = (int*)alloc(BL);
  float* xs    = alloc((size_t)B_SZ * C * L);
  float* xdblF = alloc((size_t)4 * L * 36);
  float* BmTF  = alloc((size_t)4 * L * N);
  float* CmTF  = alloc((size_t)4 * L * N);
  float* xdblU = alloc((size_t)2 * L * 40);
  float* BmTU  = alloc((size_t)2 * L * N);
  float* CmTU  = alloc((size_t)2 * L * N);
  float* yf    = alloc((size_t)B_SZ * HALF * L);
  float* yb    = alloc((size_t)B_SZ * HALF * L);
  float* yu    = alloc((size_t)B_SZ * C * L);
  float* st2m  = alloc(BL);
  float* st2r  = alloc(BL);
  float* g1    = alloc((size_t)B_SZ * C * L);
  float* fused = alloc((size_t)B_SZ * C * L);
  float* outp  = alloc((size_t)B_SZ * C * L);
  (void)ws_size; (void)in_sizes; (void)n_in; (void)out_size;

  const int pixB = B_SZ * L / 64;          // 128 blocks (256 thr)
  const int elemB = B_SZ * C * L / TPB;    // 4096

  // 0) zero the accumulators (st1 sums, rank, bnsum) — one small async fill
  hipMemsetAsync(st1s, 0, zeroBytes, stream);
  // 1) inproj with inline LN + atomic stats of xp[:,:128]
  k_conv_ln<<<dim3(L / (2 * TPB), 32, B_SZ), TPB, 0, stream>>>(
      x, C * L, ln_in_w, ln_in_b, inproj_w, inproj_b, xp, 128, 256, st1s, st1q);
  // 2) tiled dwconv (mamba LN from sums, res plain)
  k_dwconv_t<<<dim3(HH / 4, C, 2 * B_SZ), TPB, 0, stream>>>(
      xp, st1s, st1q, ln_m_w, ln_m_b, convm_w, convm_b, convr_w, convr_b, xm, xr);
  // 3) unc, rank-count, scatter-gather (also emits idx)
  k_unc<<<pixB, TPB, 0, stream>>>(xm, unc);
  k_rank<<<dim3(L / TPB, 8, B_SZ), TPB, 0, stream>>>(unc, rank);
  k_scatgath<<<elemB, TPB, 0, stream>>>(xm, rank, xs, inv, idx);
  // 4) merged scan pipelines (U writes unsorted yu directly)
  k_convx_all<<<dim3(L / TPB, 10, 6), TPB, 0, stream>>>(
      xm, xs, xpf_w, xpf_b, xpb_w, xpb_b, xpu_w, xpu_b, xdblF, xdblU);
  k_bc_all<<<dim3(L / TPB, N, 6), TPB, 0, stream>>>(
      xdblF, xdblU, BmTF, CmTF, BmTU, CmTU);
  k_scan_all<<<512, 1024, 0, stream>>>(
      xdblF, xdblU, dtf_w, dtf_b, dtb_w, dtb_b, dtu_w, dtu_b,
      xm, xs, idx, BmTF, CmTF, BmTU, CmTU,
      Alog_f, Alog_b, Alog_u, D_f, D_b, D_u, yf, yb, yu);
  // 5) epilogue
  k_gate1<8><<<dim3(L / TPB, 16, B_SZ), TPB, 0, stream>>>(
      yf, yb, ln_cat_w, ln_cat_b, yu, gate1_w, gate1_b, g1, st2m, st2r, bnsum);
  k_gate2_fuse<8><<<dim3(L / TPB, 16, B_SZ), TPB, 0, stream>>>(
      g1, bnsum, bn_g, bn_b, gate2_w, gate2_b, yu, yf, yb, st2m, st2r,
      ln_cat_w, ln_cat_b, fused);
  k_conv1x1_cat2<8><<<dim3(L / TPB, 16, B_SZ), TPB, 0, stream>>>(
      fused, xr, outproj_w, outproj_b, outp, 128);
  k_ln_cf<<<pixB, TPB, 0, stream>>>(outp, outln_w, outln_b, (float*)d_out);
}

// Round 13
// 329.326 us; speedup vs baseline: 1.5089x; 1.0325x over previous
//
#include <hip/hip_runtime.h>
#include <cstdint>
#include <cstddef>

#define TPB 256

namespace {

constexpr int B_SZ = 2;
constexpr int C    = 128;
constexpr int HALF = 64;
constexpr int L    = 4096;   // 64*64
constexpr int N    = 16;
constexpr int HH   = 64;
constexpr int WW   = 64;

// fast-math (hardware v_exp_f32/v_log_f32); ~1e-7 rel err, fine at 9.7e-2 threshold
__device__ __forceinline__ float softplusf(float x) {
  return fmaxf(x, 0.f) + __logf(1.f + __expf(-fabsf(x)));
}
__device__ __forceinline__ float sigm(float x) { return 1.f / (1.f + __expf(-x)); }

__device__ __forceinline__ unsigned long long unc_key(float u, int i) {
  unsigned m = __float_as_uint(u);
  m = (m & 0x80000000u) ? ~m : (m | 0x80000000u);   // monotone ascending map
  return ((unsigned long long)(~m) << 32) | (unsigned)i;  // ascending = descending unc, stable
}

// ---------- inproj: 1x1 conv with INLINE per-pixel LN + atomic stats of xp[:,:128] ----------
__global__ void k_conv_ln(const float* __restrict__ X, int bsX,
                          const float* __restrict__ lnw, const float* __restrict__ lnb,
                          const float* __restrict__ W, const float* __restrict__ bias,
                          float* __restrict__ Y, int I, int O,
                          float* __restrict__ st1s, float* __restrict__ st1q) {
  constexpr int O_PB = 8;
  __shared__ float Wl[O_PB * 128];
  __shared__ float aw[128], ab[128];
  const int o0 = blockIdx.y * O_PB;
  const int b  = blockIdx.z;
  for (int t = threadIdx.x; t < O_PB * I; t += TPB) {
    int i = t / O_PB, k = t % O_PB;
    Wl[t] = W[(size_t)(o0 + k) * I + i];
  }
  for (int t = threadIdx.x; t < I; t += TPB) { aw[t] = lnw[t]; ab[t] = lnb[t]; }
  __syncthreads();
  const int l0 = blockIdx.x * (2 * TPB) + threadIdx.x;
  const int l1 = l0 + TPB;
  const float* X0 = X + (size_t)b * bsX + l0;
  const float* X1 = X + (size_t)b * bsX + l1;
  float s0 = 0.f, q0 = 0.f, s1 = 0.f, q1 = 0.f;
#pragma unroll 8
  for (int i = 0; i < I; ++i) {
    float v0 = X0[(size_t)i * L], v1 = X1[(size_t)i * L];
    s0 += v0; q0 += v0 * v0; s1 += v1; q1 += v1 * v1;
  }
  const float m0 = s0 / I, m1 = s1 / I;
  const float r0 = rsqrtf(q0 / I - m0 * m0 + 1e-6f);
  const float r1 = rsqrtf(q1 / I - m1 * m1 + 1e-6f);
  float acc0[O_PB], acc1[O_PB];
#pragma unroll
  for (int k = 0; k < O_PB; ++k) { acc0[k] = bias[o0 + k]; acc1[k] = acc0[k]; }
#pragma unroll 4
  for (int i = 0; i < I; ++i) {
    float xv0 = (X0[(size_t)i * L] - m0) * r0 * aw[i] + ab[i];
    float xv1 = (X1[(size_t)i * L] - m1) * r1 * aw[i] + ab[i];
#pragma unroll
    for (int k = 0; k < O_PB; ++k) {
      acc0[k] += Wl[i * O_PB + k] * xv0;
      acc1[k] += Wl[i * O_PB + k] * xv1;
    }
  }
#pragma unroll
  for (int k = 0; k < O_PB; ++k) {
    Y[((size_t)b * O + o0 + k) * L + l0] = acc0[k];
    Y[((size_t)b * O + o0 + k) * L + l1] = acc1[k];
  }
  if (o0 < 128) {
    float ss0 = 0.f, qq0 = 0.f, ss1 = 0.f, qq1 = 0.f;
#pragma unroll
    for (int k = 0; k < O_PB; ++k) {
      ss0 += acc0[k]; qq0 += acc0[k] * acc0[k];
      ss1 += acc1[k]; qq1 += acc1[k] * acc1[k];
    }
    atomicAdd(&st1s[b * L + l0], ss0);
    atomicAdd(&st1q[b * L + l0], qq0);
    atomicAdd(&st1s[b * L + l1], ss1);
    atomicAdd(&st1q[b * L + l1], qq1);
  }
}

// ---------- depthwise 3x3 + SiLU via LDS halo tile; mode0 LN (from sum/sumsq) ----------
__global__ void k_dwconv_t(const float* __restrict__ xp,
                           const float* __restrict__ st1s, const float* __restrict__ st1q,
                           const float* __restrict__ lnw, const float* __restrict__ lnb,
                           const float* __restrict__ Wm, const float* __restrict__ bm,
                           const float* __restrict__ Wr, const float* __restrict__ br,
                           float* __restrict__ xm, float* __restrict__ xr) {
  const int c = blockIdx.y;
  const int z = blockIdx.z;
  const int b = z & 1, mode = z >> 1;     // 0: mamba (LN), 1: res
  const int h0 = blockIdx.x * 4;
  __shared__ float T[6][66];
  const float* Xc = xp + ((size_t)b * 2 * C + (mode ? C + c : c)) * L;
  const float lw = mode ? 0.f : lnw[c];
  const float lb2 = mode ? 0.f : lnb[c];
  for (int t = threadIdx.x; t < 6 * 66; t += TPB) {
    int r = t / 66, cc = t % 66 - 1;
    int hh = h0 - 1 + r;
    float v = 0.f;
    if (hh >= 0 && hh < HH && cc >= 0 && cc < WW) {
      int li = hh * WW + cc;
      v = Xc[li];
      if (mode == 0) {
        float sv = st1s[b * L + li], qv = st1q[b * L + li];
        float m = sv * (1.f / 128.f);
        float rr = rsqrtf(qv * (1.f / 128.f) - m * m + 1e-6f);
        v = (v - m) * rr * lw + lb2;
      }
    }
    T[r][t % 66] = v;
  }
  __syncthreads();
  const int hl = threadIdx.x >> 6, w = threadIdx.x & 63;
  const float* W9 = (mode ? Wr : Wm) + c * 9;
  float acc = mode ? br[c] : bm[c];
#pragma unroll
  for (int kh = 0; kh < 3; ++kh)
#pragma unroll
    for (int kw = 0; kw < 3; ++kw)
      acc += T[hl + kh][w + kw] * W9[kh * 3 + kw];
  const int l = (h0 + hl) * WW + w;
  float* Yp = mode ? xr : xm;
  Yp[((size_t)b * C + c) * L + l] = acc * sigm(acc);
}

// ---------- uncertainty per pixel ----------
__global__ void k_unc(const float* __restrict__ xm, float* __restrict__ unc) {
  const int lp = threadIdx.x & 63;
  const int wv = threadIdx.x >> 6;
  const int p  = blockIdx.x * 64 + lp;
  const int b = p / L, l = p % L;
  const float* Xp = xm + (size_t)b * C * L + l;
  float s = 0.f;
#pragma unroll 8
  for (int i = 0; i < 32; ++i) s += Xp[(size_t)(wv * 32 + i) * L];
  __shared__ float r1[4][64];
  r1[wv][lp] = s;
  __syncthreads();
  if (wv == 0) {
    float st = r1[0][lp] + r1[1][lp] + r1[2][lp] + r1[3][lp];
    float sg = sigm(st / C);
    unc[p] = -(sg * __logf(sg + 1e-6f));
  }
}

// ---------- stable rank of descending unc: rank_i = #{j: ckey_j < ckey_i} ----------
__global__ void k_rank(const float* __restrict__ unc, int* __restrict__ rankbuf) {
  constexpr int JC = 512;
  __shared__ unsigned long long K[JC];
  const int b  = blockIdx.z;
  const int j0 = blockIdx.y * JC;
  const int i  = blockIdx.x * TPB + threadIdx.x;
  for (int t = threadIdx.x; t < JC; t += TPB)
    K[t] = unc_key(unc[b * L + j0 + t], j0 + t);
  __syncthreads();
  const unsigned long long my = unc_key(unc[b * L + i], i);
  int cnt = 0;
#pragma unroll 8
  for (int j = 0; j < JC; ++j) cnt += (K[j] < my) ? 1 : 0;
  atomicAdd(&rankbuf[b * L + i], cnt);
}

// ---------- scatter-gather: xs[b,c,rank_l] = xm[b,c,l]; inv[l]=r; idx[r]=l ----------
__global__ void k_scatgath(const float* __restrict__ xm, const int* __restrict__ rankbuf,
                           float* __restrict__ xs, int* __restrict__ inv,
                           int* __restrict__ idx) {
  int t = blockIdx.x * TPB + threadIdx.x;
  int l = t % L, c = (t / L) % C, b = t / (C * L);
  int r = rankbuf[b * L + l];
  xs[((size_t)b * C + c) * L + r] = xm[t];
  if (c == 0) { inv[b * L + l] = r; idx[b * L + r] = l; }
}

// ---------- merged x-projection conv: z 0..3 = f/b dirs, z 4..5 = u (reads xs) ----------
__global__ void k_convx_all(const float* __restrict__ xm, const float* __restrict__ xs,
                            const float* __restrict__ Wf, const float* __restrict__ bf,
                            const float* __restrict__ Wb, const float* __restrict__ bb,
                            const float* __restrict__ Wu, const float* __restrict__ bu,
                            float* __restrict__ XDF, float* __restrict__ XDU) {
  const int z = blockIdx.z;
  const bool isU = z >= 4;
  const int I = isU ? 128 : 64;
  const int O = isU ? 40 : 36;
  const int o0 = blockIdx.y * 4;
  if (o0 >= O) return;                 // block-uniform
  int b, dir;
  const float *W, *bi;
  if (!isU) { dir = z >> 1; b = z & 1; W = dir ? Wb : Wf; bi = dir ? bb : bf; }
  else      { dir = 0; b = z - 4; W = Wu; bi = bu; }
  __shared__ float Wl[4 * 128];
  for (int t = threadIdx.x; t < 4 * I; t += TPB) {
    int i = t / 4, k = t % 4;
    Wl[t] = W[(size_t)(o0 + k) * I + i];
  }
  __syncthreads();
  const int l = blockIdx.x * TPB + threadIdx.x;
  const int ls = isU ? l : (dir ? (L - 1 - l) : l);
  const float* Xb = isU ? (xs + (size_t)b * C * L)
                        : (xm + ((size_t)b * C + dir * HALF) * L);
  float acc[4];
#pragma unroll
  for (int k = 0; k < 4; ++k) acc[k] = bi[o0 + k];
#pragma unroll 4
  for (int i = 0; i < I; ++i) {
    float xv = Xb[(size_t)i * L + ls];
#pragma unroll
    for (int k = 0; k < 4; ++k) acc[k] += Wl[i * 4 + k] * xv;
  }
  float* yp = isU ? (XDU + ((size_t)b * L + l) * 40 + o0)
                  : (XDF + ((size_t)z * L + l) * 36 + o0);
#pragma unroll
  for (int k = 0; k < 4; ++k) yp[k] = acc[k];
}

// ---------- merged B/C scrambled transpose ----------
__global__ void k_bc_all(const float* __restrict__ xdblF, const float* __restrict__ xdblU,
                         float* __restrict__ BmTF, float* __restrict__ CmTF,
                         float* __restrict__ BmTU, float* __restrict__ CmTU) {
  const int z = blockIdx.z;
  const bool isU = z >= 4;
  const int RT = isU ? 8 : 4, OT = isU ? 40 : 36;
  const float* src = isU ? (xdblU + (size_t)(z - 4) * L * 40)
                         : (xdblF + (size_t)z * L * 36);
  float* BT = isU ? (BmTU + (size_t)(z - 4) * L * N) : (BmTF + (size_t)z * L * N);
  float* CT = isU ? (CmTU + (size_t)(z - 4) * L * N) : (CmTF + (size_t)z * L * N);
  const int n = blockIdx.y;
  const int l2 = blockIdx.x * TPB + threadIdx.x;
  int f2 = n * L + l2;
  int lb = f2 >> 4, cb = f2 & 15;
  const float* xr2 = src + (size_t)lb * OT + RT + cb;
  size_t ob = (size_t)l2 * N + n;
  BT[ob] = xr2[0];
  CT[ob] = xr2[N];
}

// ---------- merged fused selective scan (512 blocks); U writes UNSORTED via idx ----------
// float4 LDS for dt/u (rows of 17 float4); phase-C reduce-scatter (15 shfls/16 steps).
__global__ __launch_bounds__(1024) void
k_scan_all(const float* __restrict__ xdblF, const float* __restrict__ xdblU,
           const float* __restrict__ dtf_w, const float* __restrict__ dtf_b,
           const float* __restrict__ dtb_w, const float* __restrict__ dtb_b,
           const float* __restrict__ dtu_w, const float* __restrict__ dtu_b,
           const float* __restrict__ xm, const float* __restrict__ xs,
           const int* __restrict__ idx,
           const float* __restrict__ BmTF, const float* __restrict__ CmTF,
           const float* __restrict__ BmTU, const float* __restrict__ CmTU,
           const float* __restrict__ Alog_f, const float* __restrict__ Alog_b,
           const float* __restrict__ Alog_u,
           const float* __restrict__ D_f, const float* __restrict__ D_b,
           const float* __restrict__ D_u,
           float* __restrict__ yf, float* __restrict__ yb, float* __restrict__ yu) {
  const int blk = blockIdx.x;
  const int tid = threadIdx.x;
  const bool isU = blk >= 256;
  int CsT, RT, c, b, dir;
  const float *Wdt, *bdt, *Alog, *Dv, *xdbl, *BT, *CT, *Ub;
  const int* idxb = nullptr;
  float* Y;
  int OT;
  if (!isU) {
    CsT = 64; RT = 4; OT = 36;
    int zb = blk >> 6; c = blk & 63; dir = zb >> 1; b = zb & 1;
    Wdt = dir ? dtb_w : dtf_w; bdt = dir ? dtb_b : dtf_b;
    Alog = dir ? Alog_b : Alog_f; Dv = dir ? D_b : D_f;
    xdbl = xdblF + (size_t)zb * L * 36;
    BT = BmTF + (size_t)zb * L * N; CT = CmTF + (size_t)zb * L * N;
    Ub = xm + ((size_t)b * C + dir * HALF + c) * L;
    Y = (dir ? yb : yf) + ((size_t)b * HALF + c) * L;
  } else {
    CsT = 128; RT = 8; OT = 40;
    int blk2 = blk - 256; b = blk2 >> 7; c = blk2 & 127; dir = 0;
    Wdt = dtu_w; bdt = dtu_b; Alog = Alog_u; Dv = D_u;
    xdbl = xdblU + (size_t)b * L * 40;
    BT = BmTU + (size_t)b * L * N; CT = CmTU + (size_t)b * L * N;
    Ub = xs + ((size_t)b * C + c) * L;
    idxb = idx + b * L;
    Y = yu + ((size_t)b * C + c) * L;
  }
  __shared__ float sW[1024];            // transposed: sW[r*CsT + csrc]
  __shared__ float sb2[128];
  __shared__ float4 dtL4[64 * 17];      // d  (row = 17 float4 = 68 floats, 16B-aligned)
  __shared__ float4 uL4[64 * 17];       // u
  __shared__ float sA[N][65], sH[N][65];
  for (int t = tid; t < CsT * RT; t += 1024) {
    int csrc = t / RT, r = t % RT;
    sW[r * CsT + csrc] = Wdt[t];
  }
  for (int t = tid; t < CsT; t += 1024) sb2[t] = bdt[t];
  __syncthreads();
  // ---- stage 1: dt + u into LDS (float4 stores) ----
  {
    const int chunk_d = tid >> 4;
    const int sq4 = tid & 15;
    const int sq = sq4 * 4;
    const int lsrc = isU ? (c * 32 + (chunk_d >> 1)) : (c * 64 + chunk_d);
    const float* xrp = xdbl + (size_t)lsrc * OT;
    float xr[8];
    for (int r = 0; r < RT; ++r) xr[r] = xrp[r];
    const float bcc = sb2[c];
    float dv[4], uv[4];
#pragma unroll
    for (int j = 0; j < 4; ++j) {
      int s = sq + j;
      int csrc = isU ? (((chunk_d & 1) << 6) + s) : s;
      float acc = sb2[csrc] + bcc;
      for (int r = 0; r < RT; ++r) acc += sW[r * CsT + csrc] * xr[r];
      int l = (chunk_d << 6) + s;
      dv[j] = softplusf(acc);
      uv[j] = Ub[isU ? l : (dir ? (L - 1 - l) : l)];
    }
    dtL4[chunk_d * 17 + sq4] = make_float4(dv[0], dv[1], dv[2], dv[3]);
    uL4[chunk_d * 17 + sq4]  = make_float4(uv[0], uv[1], uv[2], uv[3]);
  }
  __syncthreads();
  const int n = tid & 15;
  const int chunk = tid >> 4;
  const float a = -__expf(Alog[c * N + n]);
  const float* bp = BT + ((size_t)(chunk << 6)) * N + n;
  const float* cp = CT + ((size_t)(chunk << 6)) * N + n;
  // phase A (float4 LDS reads)
  float ap = 1.f, h = 0.f;
#pragma unroll 4
  for (int m = 0; m < 16; ++m) {
    float4 d4 = dtL4[chunk * 17 + m];
    float4 u4 = uL4[chunk * 17 + m];
    float dv[4] = {d4.x, d4.y, d4.z, d4.w};
    float uv[4] = {u4.x, u4.y, u4.z, u4.w};
#pragma unroll
    for (int jj = 0; jj < 4; ++jj) {
      int s = (m << 2) + jj;
      float bn = bp[(size_t)s * N];
      float dA = __expf(dv[jj] * a);
      ap *= dA;
      h = h * dA + dv[jj] * uv[jj] * bn;
    }
  }
  sA[n][chunk] = ap; sH[n][chunk] = h;
  __syncthreads();
  // phase B: wave-parallel cross-chunk exclusive scan (wave w owns n=w)
  {
    const int w = tid >> 6;
    const int k = tid & 63;
    float A = sA[w][k];
    float Bv = sH[w][k];
#pragma unroll
    for (int j = 1; j < 64; j <<= 1) {
      float pa = __shfl_up(A, j);
      float pb = __shfl_up(Bv, j);
      if (k >= j) { Bv = pb * A + Bv; A = pa * A; }
    }
    float hprev = __shfl_up(Bv, 1);
    sH[w][k] = (k == 0) ? 0.f : hprev;
  }
  __syncthreads();
  h = sH[n][chunk];
  // phase C: 16-step batches + reduce-scatter (15 shfls per batch)
  const float Dc = Dv[c];
  const float* uLrow = (const float*)&uL4[chunk * 17];
  const bool h1 = (n & 1) != 0, h2 = (n & 2) != 0, h3 = (n & 4) != 0, h4 = (n & 8) != 0;
  float ybuf[4];
#pragma unroll
  for (int q = 0; q < 4; ++q) {
    float v[16];
#pragma unroll
    for (int m = 0; m < 4; ++m) {
      float4 d4 = dtL4[chunk * 17 + (q << 2) + m];
      float4 u4 = uL4[chunk * 17 + (q << 2) + m];
      float dv[4] = {d4.x, d4.y, d4.z, d4.w};
      float uv[4] = {u4.x, u4.y, u4.z, u4.w};
#pragma unroll
      for (int jj = 0; jj < 4; ++jj) {
        int s = (q << 4) + (m << 2) + jj;
        float bn = bp[(size_t)s * N];
        float cn = cp[(size_t)s * N];
        float dA = __expf(dv[jj] * a);
        h = h * dA + dv[jj] * uv[jj] * bn;
        v[(m << 2) + jj] = h * cn;
      }
    }
    // reduce-scatter over the 16-lane n-group: lane n ends with sum for s = 16q+n
    float u8[8];
#pragma unroll
    for (int k2 = 0; k2 < 8; ++k2) {
      float snd = h1 ? v[2 * k2] : v[2 * k2 + 1];
      float t = __shfl_xor(snd, 1);
      u8[k2] = (h1 ? v[2 * k2 + 1] : v[2 * k2]) + t;
    }
    float u4a[4];
#pragma unroll
    for (int k2 = 0; k2 < 4; ++k2) {
      float snd = h2 ? u8[2 * k2] : u8[2 * k2 + 1];
      float t = __shfl_xor(snd, 2);
      u4a[k2] = (h2 ? u8[2 * k2 + 1] : u8[2 * k2]) + t;
    }
    float u2a[2];
#pragma unroll
    for (int k2 = 0; k2 < 2; ++k2) {
      float snd = h3 ? u4a[2 * k2] : u4a[2 * k2 + 1];
      float t = __shfl_xor(snd, 4);
      u2a[k2] = (h3 ? u4a[2 * k2 + 1] : u4a[2 * k2]) + t;
    }
    float snd = h4 ? u2a[0] : u2a[1];
    float t = __shfl_xor(snd, 8);
    float ysum = (h4 ? u2a[1] : u2a[0]) + t;
    float myu = uLrow[(q << 4) + n];
    ybuf[q] = ysum + myu * Dc;
  }
  if (!isU) {
    float* Yp = Y + (chunk << 6);
#pragma unroll
    for (int q = 0; q < 4; ++q) Yp[16 * q + n] = ybuf[q];
  } else {
    const int s0 = chunk << 6;
#pragma unroll
    for (int q = 0; q < 4; ++q) Y[idxb[s0 + 16 * q + n]] = ybuf[q];
  }
}

// ---------- gate1: inline cat-LN stats + conv + BN partial sums ----------
template <int O_PB>
__global__ void k_gate1(const float* __restrict__ yf, const float* __restrict__ yb,
                        const float* __restrict__ lncw, const float* __restrict__ lncb,
                        const float* __restrict__ yu,
                        const float* __restrict__ W, const float* __restrict__ bias,
                        float* __restrict__ g1,
                        float* __restrict__ st2m, float* __restrict__ st2r,
                        float* __restrict__ bnsum) {
  __shared__ float Wl[O_PB * 256];
  __shared__ float cw[128], cb2[128];
  __shared__ float part[2][O_PB][4];
  const int o0 = blockIdx.y * O_PB;
  const int b  = blockIdx.z;
  for (int t = threadIdx.x; t < O_PB * 256; t += TPB) {
    int i = t / O_PB, k = t % O_PB;
    Wl[t] = W[(size_t)(o0 + k) * 256 + i];
  }
  for (int t = threadIdx.x; t < 128; t += TPB) { cw[t] = lncw[t]; cb2[t] = lncb[t]; }
  __syncthreads();
  const int l = blockIdx.x * TPB + threadIdx.x;
  const float* f0 = yf + (size_t)b * HALF * L + l;
  const float* b0 = yb + (size_t)b * HALF * L + (L - 1 - l);
  const float* u0 = yu + (size_t)b * C * L + l;
  float s = 0.f, s2 = 0.f;
#pragma unroll 8
  for (int i = 0; i < 64; ++i) { float v = f0[(size_t)i * L]; s += v; s2 += v * v; }
#pragma unroll 8
  for (int i = 0; i < 64; ++i) { float v = b0[(size_t)i * L]; s += v; s2 += v * v; }
  const float m = s / C;
  const float r = rsqrtf(s2 / C - m * m + 1e-6f);
  if (blockIdx.y == 0) { st2m[b * L + l] = m; st2r[b * L + l] = r; }
  float acc[O_PB];
#pragma unroll
  for (int k = 0; k < O_PB; ++k) acc[k] = bias[o0 + k];
#pragma unroll 4
  for (int i = 0; i < 64; ++i) {
    float cv = (f0[(size_t)i * L] - m) * r * cw[i] + cb2[i];
#pragma unroll
    for (int k = 0; k < O_PB; ++k) acc[k] += Wl[i * O_PB + k] * cv;
  }
#pragma unroll 4
  for (int i = 0; i < 64; ++i) {
    float cv = (b0[(size_t)i * L] - m) * r * cw[64 + i] + cb2[64 + i];
#pragma unroll
    for (int k = 0; k < O_PB; ++k) acc[k] += Wl[(64 + i) * O_PB + k] * cv;
  }
#pragma unroll 4
  for (int i = 0; i < 128; ++i) {
    float xv = u0[(size_t)i * L];
#pragma unroll
    for (int k = 0; k < O_PB; ++k) acc[k] += Wl[(128 + i) * O_PB + k] * xv;
  }
#pragma unroll
  for (int k = 0; k < O_PB; ++k)
    g1[((size_t)b * C + o0 + k) * L + l] = acc[k];
  const int wv = threadIdx.x >> 6, lnn = threadIdx.x & 63;
#pragma unroll
  for (int k = 0; k < O_PB; ++k) {
    float v = acc[k];
    v += __shfl_xor(v, 1);  v += __shfl_xor(v, 2);  v += __shfl_xor(v, 4);
    v += __shfl_xor(v, 8);  v += __shfl_xor(v, 16); v += __shfl_xor(v, 32);
    if (lnn == 0) part[0][k][wv] = v;
    float q = acc[k] * acc[k];
    q += __shfl_xor(q, 1);  q += __shfl_xor(q, 2);  q += __shfl_xor(q, 4);
    q += __shfl_xor(q, 8);  q += __shfl_xor(q, 16); q += __shfl_xor(q, 32);
    if (lnn == 0) part[1][k][wv] = q;
  }
  __syncthreads();
  if (threadIdx.x < 2 * O_PB) {
    int which = threadIdx.x >= O_PB, k = threadIdx.x % O_PB;
    float v = part[which][k][0] + part[which][k][1] + part[which][k][2] + part[which][k][3];
    atomicAdd(&bnsum[which * 128 + o0 + k], v);
  }
}

// ---------- gate2: BN(from sums)+relu on loads; epilogue sigmoid+fuse ----------
template <int O_PB>
__global__ void k_gate2_fuse(const float* __restrict__ g1,
                             const float* __restrict__ bnsum,
                             const float* __restrict__ bn_g, const float* __restrict__ bn_b,
                             const float* __restrict__ W, const float* __restrict__ bias,
                             const float* __restrict__ yu,
                             const float* __restrict__ yf, const float* __restrict__ yb,
                             const float* __restrict__ mean2, const float* __restrict__ rinv2,
                             const float* __restrict__ lncw, const float* __restrict__ lncb,
                             float* __restrict__ fused) {
  __shared__ float Wl[O_PB * 128];
  __shared__ float sc[128], sh[128];
  __shared__ float cwo[O_PB], cbo[O_PB];
  const int o0 = blockIdx.y * O_PB;
  const int b  = blockIdx.z;
  for (int t = threadIdx.x; t < O_PB * 128; t += TPB) {
    int i = t / O_PB, k = t % O_PB;
    Wl[t] = W[(size_t)(o0 + k) * 128 + i];
  }
  for (int t = threadIdx.x; t < 128; t += TPB) {
    float sv = bnsum[t], qv = bnsum[128 + t];
    float mean = sv / (B_SZ * L);
    float var  = qv / (B_SZ * L) - mean * mean;
    float scv = bn_g[t] * rsqrtf(var + 1e-5f);
    sc[t] = scv;
    sh[t] = bn_b[t] - mean * scv;
  }
  if (threadIdx.x < O_PB) {
    cwo[threadIdx.x] = lncw[o0 + threadIdx.x];
    cbo[threadIdx.x] = lncb[o0 + threadIdx.x];
  }
  __syncthreads();
  const int l = blockIdx.x * TPB + threadIdx.x;
  const float m = mean2[b * L + l], r = rinv2[b * L + l];
  const float* Xb = g1 + (size_t)b * C * L + l;
  float acc[O_PB];
#pragma unroll
  for (int k = 0; k < O_PB; ++k) acc[k] = bias[o0 + k];
#pragma unroll 4
  for (int i = 0; i < 128; ++i) {
    float v = fmaxf(Xb[(size_t)i * L] * sc[i] + sh[i], 0.f);
#pragma unroll
    for (int k = 0; k < O_PB; ++k) acc[k] += Wl[i * O_PB + k] * v;
  }
#pragma unroll
  for (int k = 0; k < O_PB; ++k) {
    int o = o0 + k;
    float g = sigm(acc[k]);
    float yuv = yu[((size_t)b * C + o) * L + l];
    float yv = (o < 64) ? yf[((size_t)b * HALF + o) * L + l]
                        : yb[((size_t)b * HALF + (o - 64)) * L + (L - 1 - l)];
    float cv = (yv - m) * r * cwo[k] + cbo[k];
    fused[((size_t)b * C + o) * L + l] = g * yuv + (1.f - g) * cv;
  }
}

// ---------- outproj: 1x1 conv over concat([fused, xr]) ----------
template <int O_PB>
__global__ void k_conv1x1_cat2(const float* __restrict__ X1, const float* __restrict__ X2,
                               const float* __restrict__ W, const float* __restrict__ bias,
                               float* __restrict__ Y, int O) {
  __shared__ float Wl[O_PB * 256];
  const int o0 = blockIdx.y * O_PB;
  const int b  = blockIdx.z;
  for (int t = threadIdx.x; t < O_PB * 256; t += TPB) {
    int i = t / O_PB, k = t % O_PB;
    Wl[t] = W[(size_t)(o0 + k) * 256 + i];
  }
  __syncthreads();
  const int l = blockIdx.x * TPB + threadIdx.x;
  const float* Xb1 = X1 + (size_t)b * C * L + l;
  const float* Xb2 = X2 + (size_t)b * C * L + l;
  float acc[O_PB];
#pragma unroll
  for (int k = 0; k < O_PB; ++k) acc[k] = bias[o0 + k];
#pragma unroll 4
  for (int i = 0; i < 128; ++i) {
    float xv = Xb1[(size_t)i * L];
#pragma unroll
    for (int k = 0; k < O_PB; ++k) acc[k] += Wl[i * O_PB + k] * xv;
  }
#pragma unroll 4
  for (int i = 0; i < 128; ++i) {
    float xv = Xb2[(size_t)i * L];
#pragma unroll
    for (int k = 0; k < O_PB; ++k) acc[k] += Wl[(128 + i) * O_PB + k] * xv;
  }
#pragma unroll
  for (int k = 0; k < O_PB; ++k)
    Y[((size_t)b * O + o0 + k) * L + l] = acc[k];
}

// ---------- final channel LN ----------
__global__ void k_ln_cf(const float* __restrict__ X,
                        const float* __restrict__ w, const float* __restrict__ bchan,
                        float* __restrict__ Y) {
  const int lp = threadIdx.x & 63;
  const int wv = threadIdx.x >> 6;
  const int p  = blockIdx.x * 64 + lp;
  const int b = p / L, l = p % L;
  const float* Xp = X + (size_t)b * C * L + l;
  float s = 0.f, s2 = 0.f;
#pragma unroll 8
  for (int i = 0; i < 32; ++i) {
    float v = Xp[(size_t)(wv * 32 + i) * L];
    s += v; s2 += v * v;
  }
  __shared__ float r1[4][64], r2[4][64];
  r1[wv][lp] = s; r2[wv][lp] = s2;
  __syncthreads();
  float st  = r1[0][lp] + r1[1][lp] + r1[2][lp] + r1[3][lp];
  float s2t = r2[0][lp] + r2[1][lp] + r2[2][lp] + r2[3][lp];
  float mean = st / C;
  float rinv = rsqrtf(s2t / C - mean * mean + 1e-6f);
  float* Yp = Y + (size_t)b * C * L + l;
#pragma unroll 8
  for (int i = 0; i < 32; ++i) {
    int c = wv * 32 + i;
    float v = Xp[(size_t)c * L];
    Yp[(size_t)c * L] = w[c] * (v - mean) * rinv + bchan[c];
  }
}

} // namespace

extern "C" void kernel_launch(void* const* d_in, const int* in_sizes, int n_in,
                              void* d_out, int out_size, void* d_ws, size_t ws_size,
                              hipStream_t stream) {
  const float* x         = (const float*)d_in[0];
  const float* ln_in_w   = (const float*)d_in[1];
  const float* ln_in_b   = (const float*)d_in[2];
  const float* inproj_w  = (const float*)d_in[3];
  const float* inproj_b  = (const float*)d_in[4];
  const float* ln_m_w    = (const float*)d_in[5];
  const float* ln_m_b    = (const float*)d_in[6];
  const float* convm_w   = (const float*)d_in[7];
  const float* convm_b   = (const float*)d_in[8];
  const float* convr_w   = (const float*)d_in[9];
  const float* convr_b   = (const float*)d_in[10];
  const float* ln_cat_w  = (const float*)d_in[11];
  const float* ln_cat_b  = (const float*)d_in[12];
  const float* xpf_w     = (const float*)d_in[13];
  const float* xpf_b     = (const float*)d_in[14];
  const float* dtf_w     = (const float*)d_in[15];
  const float* dtf_b     = (const float*)d_in[16];
  const float* Alog_f    = (const float*)d_in[17];
  const float* D_f       = (const float*)d_in[18];
  const float* xpb_w     = (const float*)d_in[19];
  const float* xpb_b     = (const float*)d_in[20];
  const float* dtb_w     = (const float*)d_in[21];
  const float* dtb_b     = (const float*)d_in[22];
  const float* Alog_b    = (const float*)d_in[23];
  const float* D_b       = (const float*)d_in[24];
  const float* xpu_w     = (const float*)d_in[25];
  const float* xpu_b     = (const float*)d_in[26];
  const float* dtu_w     = (const float*)d_in[27];
  const float* dtu_b     = (const float*)d_in[28];
  const float* Alog_u    = (const float*)d_in[29];
  const float* D_u       = (const float*)d_in[30];
  const float* gate1_w   = (const float*)d_in[31];
  const float* gate1_b   = (const float*)d_in[32];
  const float* bn_g      = (const float*)d_in[33];
  const float* bn_b      = (const float*)d_in[34];
  const float* gate2_w   = (const float*)d_in[35];
  const float* gate2_b   = (const float*)d_in[36];
  const float* outproj_w = (const float*)d_in[37];
  const float* outproj_b = (const float*)d_in[38];
  const float* outln_w   = (const float*)d_in[39];
  const float* outln_b   = (const float*)d_in[40];

  float* ws = (float*)d_ws;
  size_t off = 0;
  auto alloc = [&](size_t n) { float* p = ws + off; off += n; return p; };

  const size_t BL = (size_t)B_SZ * L;
  // zero-initialized region (one memset): st1s, st1q, rank, bnsum — contiguous
  float* st1s  = alloc(BL);
  float* st1q  = alloc(BL);
  int*   rank  = (int*)alloc(BL);
  float* bnsum = alloc(256);
  const size_t zeroBytes = (3 * BL + 256) * sizeof(float);

  float* xp    = alloc((size_t)B_SZ * 2 * C * L);
  float* xm    = alloc((size_t)B_SZ * C * L);
  float* xr    = alloc((size_t)B_SZ * C * L);
  float* unc   = alloc(BL);
  int*   inv   = (int*)alloc(BL);
  int*   idx   = (int*)alloc(BL);
  float* xs    = alloc((size_t)B_SZ * C * L);
  float* xdblF = alloc((size_t)4 * L * 36);
  float* BmTF  = alloc((size_t)4 * L * N);
  float* CmTF  = alloc((size_t)4 * L * N);
  float* xdblU = alloc((size_t)2 * L * 40);
  float* BmTU  = alloc((size_t)2 * L * N);
  float* CmTU  = alloc((size_t)2 * L * N);
  float* yf    = alloc((size_t)B_SZ * HALF * L);
  float* yb    = alloc((size_t)B_SZ * HALF * L);
  float* yu    = alloc((size_t)B_SZ * C * L);
  float* st2m  = alloc(BL);
  float* st2r  = alloc(BL);
  float* g1    = alloc((size_t)B_SZ * C * L);
  float* fused = alloc((size_t)B_SZ * C * L);
  float* outp  = alloc((size_t)B_SZ * C * L);
  (void)ws_size; (void)in_sizes; (void)n_in; (void)out_size;

  const int pixB = B_SZ * L / 64;          // 128 blocks (256 thr)
  const int elemB = B_SZ * C * L / TPB;    // 4096

  // 0) zero the accumulators (st1 sums, rank, bnsum) — one small async fill
  hipMemsetAsync(st1s, 0, zeroBytes, stream);
  // 1) inproj with inline LN + atomic stats of xp[:,:128]
  k_conv_ln<<<dim3(L / (2 * TPB), 32, B_SZ), TPB, 0, stream>>>(
      x, C * L, ln_in_w, ln_in_b, inproj_w, inproj_b, xp, 128, 256, st1s, st1q);
  // 2) tiled dwconv (mamba LN from sums, res plain)
  k_dwconv_t<<<dim3(HH / 4, C, 2 * B_SZ), TPB, 0, stream>>>(
      xp, st1s, st1q, ln_m_w, ln_m_b, convm_w, convm_b, convr_w, convr_b, xm, xr);
  // 3) unc, rank-count, scatter-gather (also emits idx)
  k_unc<<<pixB, TPB, 0, stream>>>(xm, unc);
  k_rank<<<dim3(L / TPB, 8, B_SZ), TPB, 0, stream>>>(unc, rank);
  k_scatgath<<<elemB, TPB, 0, stream>>>(xm, rank, xs, inv, idx);
  // 4) merged scan pipelines (U writes unsorted yu directly)
  k_convx_all<<<dim3(L / TPB, 10, 6), TPB, 0, stream>>>(
      xm, xs, xpf_w, xpf_b, xpb_w, xpb_b, xpu_w, xpu_b, xdblF, xdblU);
  k_bc_all<<<dim3(L / TPB, N, 6), TPB, 0, stream>>>(
      xdblF, xdblU, BmTF, CmTF, BmTU, CmTU);
  k_scan_all<<<512, 1024, 0, stream>>>(
      xdblF, xdblU, dtf_w, dtf_b, dtb_w, dtb_b, dtu_w, dtu_b,
      xm, xs, idx, BmTF, CmTF, BmTU, CmTU,
      Alog_f, Alog_b, Alog_u, D_f, D_b, D_u, yf, yb, yu);
  // 5) epilogue
  k_gate1<8><<<dim3(L / TPB, 16, B_SZ), TPB, 0, stream>>>(
      yf, yb, ln_cat_w, ln_cat_b, yu, gate1_w, gate1_b, g1, st2m, st2r, bnsum);
  k_gate2_fuse<8><<<dim3(L / TPB, 16, B_SZ), TPB, 0, stream>>>(
      g1, bnsum, bn_g, bn_b, gate2_w, gate2_b, yu, yf, yb, st2m, st2r,
      ln_cat_w, ln_cat_b, fused);
  k_conv1x1_cat2<8><<<dim3(L / TPB, 16, B_SZ), TPB, 0, stream>>>(
      fused, xr, outproj_w, outproj_b, outp, 128);
  k_ln_cf<<<pixB, TPB, 0, stream>>>(outp, outln_w, outln_b, (float*)d_out);
}